// Round 3
// baseline (484.515 us; speedup 1.0000x reference)
//
#include <hip/hip_runtime.h>

// FlashMultiHeadAttention  B=4 S=2048 HIDDEN=1024 H=16 Dh=64 (fp32 I/O)
// r8: attn occupancy fix. r7 was latency-bound with grid=512 blocks x 4 waves
//     = 2 waves/SIMD (occ 19.5%, MfmaUtil 11, VALUBusy 40 — nothing saturated).
//     Restructure: 8 waves/block x 16 q/wave (512 thr), same 512 uniform blocks
//     -> 16 waves/CU (4/SIMD), per-wave state halved, VGPR<=128 via
//     __launch_bounds__(512,4). Work, balance, LDS, traffic unchanged.
// ws (u16 elems, 96 MB): Qw[0,8M) Kw[8M,16M) Vt[16M,24M) Ow[24M,32M) rel'[32M,48M)
//     aliases: Xq_bf16 = Ow region, Xk/Xv_bf16 = rel' region (rel_perm runs after
//     qkv), Wq/Wk/Wv_bf16 = d_out scratch, Wo_bf16 = Qw region (dead after attn).

#define SEQ 2048
#define NH 16
#define DH 64
#define HID 1024
#define QSCALE 0.18033688011112f   // 0.125 * log2(e)

typedef short bf16x8 __attribute__((ext_vector_type(8)));
typedef float f32x4  __attribute__((ext_vector_type(4)));
typedef unsigned short u16;
typedef unsigned short u16x4 __attribute__((ext_vector_type(4)));
typedef unsigned short u16x8 __attribute__((ext_vector_type(8)));

__device__ __forceinline__ float b2f(u16 u) {
    union { unsigned i; float f; } x; x.i = ((unsigned)u) << 16; return x.f;
}
__device__ __forceinline__ u16 f2b(float f) {
    union { float f; unsigned i; } x; x.f = f;
    unsigned r = x.i + 0x7fffu + ((x.i >> 16) & 1u);
    return (u16)(r >> 16);
}

typedef const __attribute__((address_space(1))) unsigned int guint;
typedef __attribute__((address_space(3))) unsigned int luint;
__device__ __forceinline__ void gload_lds16(const u16* g, u16* l) {
    __builtin_amdgcn_global_load_lds((guint*)g, (luint*)l, 16, 0, 0);
}

// ---------------- fp32 -> bf16 bulk convert (vectorized, grid-stride) ----------------
__global__ __launch_bounds__(256) void cvt_bf16_kernel(
    const float* __restrict__ in, u16* __restrict__ out, int n8)
{
    int i = blockIdx.x * 256 + threadIdx.x;
    const int stride = gridDim.x * 256;
    for (; i < n8; i += stride) {
        f32x4 a = *(const f32x4*)(in + (size_t)i * 8);
        f32x4 b = *(const f32x4*)(in + (size_t)i * 8 + 4);
        u16x8 o;
#pragma unroll
        for (int j = 0; j < 4; ++j) { o[j] = f2b(a[j]); o[j + 4] = f2b(b[j]); }
        *(u16x8*)(out + (size_t)i * 8) = o;
    }
}

// ---------------- rel -> bf16, pre-scaled, permuted to MFMA C-fragment order ----------
// out[b][qt16 (128)][kt64 (32)][lane (64)][nt (4)][g (4)]  where for element (q,k):
//   qt16=q>>4, kt64=k>>6, lane=((q>>2)&3)*16 + (k&15), nt=(k>>4)&3, g=q&3
__global__ __launch_bounds__(256) void rel_perm_kernel(
    const float* __restrict__ rel, u16* __restrict__ out)
{
    __shared__ u16 pl[4096];             // 4 qt16-subtiles x 1024
    const int t   = threadIdx.x;
    const int blk = blockIdx.x;          // 4096 = 4b x 32qc x 32kc
    const int b   = blk >> 10;
    const int qc  = (blk >> 5) & 31;
    const int kc  = blk & 31;
    const int qloc  = t >> 2;            // 0..63
    const int kloc0 = (t & 3) << 4;      // 0,16,32,48

    const float* src = rel + ((size_t)b * SEQ + qc * 64 + qloc) * SEQ + kc * 64 + kloc0;
    const int qt   = qloc >> 4;
    const int quad = (qloc >> 2) & 3;
    const int g    = qloc & 3;
    const int nt   = t & 3;
    u16* dst = pl + qt * 1024 + quad * 256 + nt * 4 + g;
#pragma unroll
    for (int c = 0; c < 4; ++c) {
        f32x4 x = *(const f32x4*)(src + c * 4);
#pragma unroll
        for (int j = 0; j < 4; ++j)
            dst[(c * 4 + j) * 16] = f2b(x[j] * QSCALE);
    }
    __syncthreads();
    const size_t obase = (((size_t)b * 128 + qc * 4) * 32 + kc) * 1024;
#pragma unroll
    for (int q2 = 0; q2 < 4; ++q2)
        *(u16x4*)(out + obase + (size_t)q2 * 32768 + t * 4) =
            *(const u16x4*)(pl + q2 * 1024 + t * 4);
}

// ---------------- QKV projection: bf16 LDS-staged GEMM, Y = X @ W^T + b ----------------
__global__ __launch_bounds__(256) void qkv_proj_kernel(
    const u16* __restrict__ xq, const u16* __restrict__ xk, const u16* __restrict__ xv,
    const u16* __restrict__ wq, const u16* __restrict__ wk, const u16* __restrict__ wv,
    const float* __restrict__ bq, const float* __restrict__ bk, const float* __restrict__ bv,
    u16* __restrict__ Qw, u16* __restrict__ Kw, u16* __restrict__ Vw)
{
    __shared__ __align__(16) u16 As[128 * 32];
    __shared__ __align__(16) u16 Bs[128 * 32];

    const int tid  = threadIdx.x;
    const int w    = tid >> 6;
    const int lane = tid & 63;
    const int l16  = lane & 15;
    const int quad = lane >> 4;

    const int bid = blockIdx.x;
    const int sel = bid >> 9;            // 0=q 1=k 2=v  (512 blocks each)
    const int rem = bid & 511;
    const int tm = rem >> 3, tn = rem & 7;
    const int m0 = tm << 7, n0 = tn << 7;

    const u16* X    = sel == 0 ? xq : (sel == 1 ? xk : xv);
    const u16* W    = sel == 0 ? wq : (sel == 1 ? wk : wv);
    const float* bias = sel == 0 ? bq : (sel == 1 ? bk : bv);

    const int crow = lane >> 2;          // row within chunk 0..15
    const int cofs = (lane & 3) << 3;    // elem offset 0,8,16,24

    f32x4 acc[4][4];
    const f32x4 zero = {0.f, 0.f, 0.f, 0.f};
#pragma unroll
    for (int r = 0; r < 4; ++r)
#pragma unroll
        for (int c = 0; c < 4; ++c) acc[r][c] = zero;

    const int wr = (w >> 1) << 6;
    const int wc = (w & 1) << 6;

    for (int k0 = 0; k0 < 1024; k0 += 32) {
#pragma unroll
        for (int c = 0; c < 2; ++c) {
            const int ch  = w + c * 4;
            const int row = ch * 16 + crow;
            gload_lds16(X + (size_t)(m0 + row) * 1024 + k0 + cofs, As + ch * 512 + lane * 8);
            gload_lds16(W + (size_t)(n0 + row) * 1024 + k0 + cofs, Bs + ch * 512 + lane * 8);
        }
        __syncthreads();
        bf16x8 a[4], b[4];
#pragma unroll
        for (int r = 0; r < 4; ++r) a[r] = *(const bf16x8*)(As + (wr + r * 16 + l16) * 32 + quad * 8);
#pragma unroll
        for (int c = 0; c < 4; ++c) b[c] = *(const bf16x8*)(Bs + (wc + c * 16 + l16) * 32 + quad * 8);
#pragma unroll
        for (int r = 0; r < 4; ++r)
#pragma unroll
            for (int c = 0; c < 4; ++c)
                acc[r][c] = __builtin_amdgcn_mfma_f32_16x16x32_bf16(a[r], b[c], acc[r][c], 0, 0, 0);
        __syncthreads();
    }

    // C layout: col(n)=lane&15, row(m)=quad*4+reg
#pragma unroll
    for (int c = 0; c < 4; ++c) {
        const int n = n0 + wc + c * 16 + l16;
        const float bn = bias[n];
        const int h = n >> 6, d = n & 63;
#pragma unroll
        for (int r = 0; r < 4; ++r) {
#pragma unroll
            for (int g = 0; g < 4; ++g) {
                const int m  = m0 + wr + r * 16 + quad * 4 + g;
                const int b_ = m >> 11, s_ = m & 2047;
                const float val = acc[r][c][g] + bn;
                if (sel == 0)
                    Qw[(((size_t)(b_ * 16 + h)) * 2048 + s_) * 64 + d] = f2b(val * QSCALE);
                else if (sel == 1)
                    Kw[(((size_t)(b_ * 16 + h)) * 2048 + s_) * 64 + d] = f2b(val);
                else
                    Vw[(((size_t)(b_ * 16 + h)) * 64 + d) * 2048 + s_] = f2b(val);  // transposed
            }
        }
    }
}

// ---------------- Flash attention: 8 waves/block, 16 q/wave, 2 strips/block ----------------
__global__ __launch_bounds__(512, 4) void attn_kernel(
    const u16* __restrict__ Qb, const u16* __restrict__ Kb,
    const u16* __restrict__ Vb, const u16* __restrict__ relb,
    u16* __restrict__ Ob)
{
    __shared__ __align__(16) u16 lds[18432];   // Ks 64x72 | Vt 64x72 | Pl 8x(16x72)
    u16* Ks = lds;
    u16* Vt = lds + 4608;

    const int tid  = threadIdx.x;              // 0..511
    const int w    = tid >> 6;                 // 0..7
    const int lane = tid & 63;
    const int l16  = lane & 15;
    const int quad = lane >> 4;
    u16* Pl = lds + 9216 + w * 1152;           // 16 rows x 72

    const int bh = blockIdx.x & 63;
    const int p  = blockIdx.x >> 6;            // 0..7 strip pair
    const int b  = bh >> 4, h = bh & 15;

    const u16* Qp = Qb + (size_t)bh * SEQ * DH;
    const u16* Kg = Kb + (size_t)bh * SEQ * DH;
    const u16* Vg = Vb + (size_t)bh * DH * SEQ;

    // staging: 512 16B-chunks per tile kind, exactly 1 per thread
    const int r0 = tid >> 3, o0 = (tid & 7) << 3;

    for (int sidx = 0; sidx < 2; ++sidx) {
        const int qb  = sidx ? (15 - p) : p;
        const int q0w = qb * 128 + w * 16;     // wave's 16-query window

        // Q A-fragments (persistent; Q pre-scaled by QSCALE)
        bf16x8 qa[2];
#pragma unroll
        for (int ks = 0; ks < 2; ++ks)
            qa[ks] = *(const bf16x8*)(Qp + (size_t)(q0w + l16) * 64 + ks * 32 + quad * 8);

        f32x4 o[4], mrow, lrow;
        const f32x4 zero = {0.f, 0.f, 0.f, 0.f};
        const f32x4 ninf = {-1e30f, -1e30f, -1e30f, -1e30f};
        mrow = ninf; lrow = zero;
#pragma unroll
        for (int dt = 0; dt < 4; ++dt) o[dt] = zero;

        const int ntiles  = qb * 2 + 2;              // staged by the block
        const int mytiles = qb * 2 + (w >> 2) + 1;   // processed by this wave

        // rel (permuted) base: idx = (b*128+qt)*32768 + kt*1024 + lane*16
        const u16* relW = relb + ((size_t)(b * 128 + (q0w >> 4))) * 32768 + (size_t)lane * 16;

        // prefetch tile 0
        bf16x8 kreg = *(const bf16x8*)(Kg + (size_t)r0 * 64 + o0);
        bf16x8 vreg = *(const bf16x8*)(Vg + (size_t)r0 * 2048 + o0);
        bf16x8 rr0 = *(const bf16x8*)(relW);
        bf16x8 rr1 = *(const bf16x8*)(relW + 8);

        for (int kt = 0; kt < ntiles; ++kt) {
            const int k0 = kt << 6;
            // regs -> LDS
            *(bf16x8*)(Ks + r0 * 72 + o0) = kreg;
            *(bf16x8*)(Vt + r0 * 72 + o0) = vreg;

            // s-init from prefetched rel regs (pure VALU, before barrier)
            f32x4 s[4];
            if (kt < mytiles) {
#pragma unroll
                for (int nt = 0; nt < 4; ++nt)
#pragma unroll
                    for (int g = 0; g < 4; ++g)
                        s[nt][g] = b2f((u16)((nt < 2 ? rr0 : rr1)[(nt & 1) * 4 + g]));
            }

            // issue next tile's global loads (latency hidden under compute)
            const int ktn = (kt + 1 < ntiles) ? kt + 1 : kt;
            const int kn  = ktn << 6;
            kreg = *(const bf16x8*)(Kg + (size_t)(kn + r0) * 64 + o0);
            vreg = *(const bf16x8*)(Vg + (size_t)r0 * 2048 + kn + o0);
            rr0  = *(const bf16x8*)(relW + (size_t)ktn * 1024);
            rr1  = *(const bf16x8*)(relW + (size_t)ktn * 1024 + 8);
            __syncthreads();

            if (kt < mytiles) {
                // ---- scores: C init = rel' (done above), MFMA adds scaled QK^T ----
#pragma unroll
                for (int nt = 0; nt < 4; ++nt) {
                    bf16x8 kb0 = *(const bf16x8*)(Ks + (nt * 16 + l16) * 72 + quad * 8);
                    bf16x8 kb1 = *(const bf16x8*)(Ks + (nt * 16 + l16) * 72 + 32 + quad * 8);
                    s[nt] = __builtin_amdgcn_mfma_f32_16x16x32_bf16(qa[0], kb0, s[nt], 0, 0, 0);
                    s[nt] = __builtin_amdgcn_mfma_f32_16x16x32_bf16(qa[1], kb1, s[nt], 0, 0, 0);
                }
                // ---- causal mask (diagonal tile only) ----
                if (kt == mytiles - 1) {
#pragma unroll
                    for (int nt = 0; nt < 4; ++nt)
#pragma unroll
                        for (int g = 0; g < 4; ++g) {
                            const int q = q0w + quad * 4 + g;
                            const int k = k0 + nt * 16 + l16;
                            if (k > q) s[nt][g] = -1e30f;
                        }
                }
                // ---- online softmax (exp2 domain) ----
                {
                    f32x4 t;
#pragma unroll
                    for (int g = 0; g < 4; ++g)
                        t[g] = fmaxf(fmaxf(s[0][g], s[1][g]), fmaxf(s[2][g], s[3][g]));
#pragma unroll
                    for (int off = 1; off < 16; off <<= 1)
#pragma unroll
                        for (int g = 0; g < 4; ++g)
                            t[g] = fmaxf(t[g], __shfl_xor(t[g], off, 64));
                    f32x4 mn, alpha;
#pragma unroll
                    for (int g = 0; g < 4; ++g) {
                        mn[g] = fmaxf(mrow[g], t[g]);
                        alpha[g] = __builtin_amdgcn_exp2f(mrow[g] - mn[g]);
                    }
                    mrow = mn;
#pragma unroll
                    for (int g = 0; g < 4; ++g) lrow[g] *= alpha[g];
#pragma unroll
                    for (int dt = 0; dt < 4; ++dt)
#pragma unroll
                        for (int g = 0; g < 4; ++g) o[dt][g] *= alpha[g];
#pragma unroll
                    for (int nt = 0; nt < 4; ++nt)
#pragma unroll
                        for (int g = 0; g < 4; ++g)
                            s[nt][g] = __builtin_amdgcn_exp2f(s[nt][g] - mn[g]);
                    f32x4 rs;
#pragma unroll
                    for (int g = 0; g < 4; ++g)
                        rs[g] = (s[0][g] + s[1][g]) + (s[2][g] + s[3][g]);
#pragma unroll
                    for (int off = 1; off < 16; off <<= 1)
#pragma unroll
                        for (int g = 0; g < 4; ++g)
                            rs[g] += __shfl_xor(rs[g], off, 64);
#pragma unroll
                    for (int g = 0; g < 4; ++g) lrow[g] += rs[g];
                }
                // ---- P -> bf16 -> per-wave LDS ----
#pragma unroll
                for (int nt = 0; nt < 4; ++nt)
#pragma unroll
                    for (int g = 0; g < 4; ++g)
                        Pl[(quad * 4 + g) * 72 + nt * 16 + l16] = f2b(s[nt][g]);
                // ---- PV ----
                bf16x8 pa[2];
#pragma unroll
                for (int ks = 0; ks < 2; ++ks)
                    pa[ks] = *(const bf16x8*)(Pl + l16 * 72 + ks * 32 + quad * 8);
#pragma unroll
                for (int dt = 0; dt < 4; ++dt) {
                    bf16x8 vb0 = *(const bf16x8*)(Vt + (dt * 16 + l16) * 72 + quad * 8);
                    bf16x8 vb1 = *(const bf16x8*)(Vt + (dt * 16 + l16) * 72 + 32 + quad * 8);
                    o[dt] = __builtin_amdgcn_mfma_f32_16x16x32_bf16(pa[0], vb0, o[dt], 0, 0, 0);
                    o[dt] = __builtin_amdgcn_mfma_f32_16x16x32_bf16(pa[1], vb1, o[dt], 0, 0, 0);
                }
            }
            __syncthreads();
        }

        // ---- epilogue: O/l -> per-wave LDS -> coalesced stores ----
        {
            f32x4 linv;
#pragma unroll
            for (int g = 0; g < 4; ++g) linv[g] = 1.0f / lrow[g];
#pragma unroll
            for (int dt = 0; dt < 4; ++dt)
#pragma unroll
                for (int g = 0; g < 4; ++g)
                    Pl[(quad * 4 + g) * 72 + dt * 16 + l16] = f2b(o[dt][g] * linv[g]);
        }
#pragma unroll
        for (int pp = 0; pp < 2; ++pp) {
            const int c = lane + pp * 64;
            const int row = c >> 3, col = (c & 7) << 3;
            bf16x8 t = *(const bf16x8*)(Pl + row * 72 + col);
            *(bf16x8*)(Ob + ((size_t)b * SEQ + q0w + row) * HID + h * DH + col) = t;
        }
    }
}

// ---------------- Output projection: bf16 LDS-staged GEMM, out = O @ Wout^T + bout ----------------
__global__ __launch_bounds__(256) void out_proj_kernel(
    const u16* __restrict__ X, const u16* __restrict__ W,
    const float* __restrict__ bias, float* __restrict__ out)
{
    __shared__ __align__(16) u16 As[128 * 32];
    __shared__ __align__(16) u16 Bs[128 * 32];

    const int tid  = threadIdx.x;
    const int w    = tid >> 6;
    const int lane = tid & 63;
    const int l16  = lane & 15;
    const int quad = lane >> 4;

    const int bid = blockIdx.x;
    const int tm = bid >> 3, tn = bid & 7;
    const int m0 = tm << 7, n0 = tn << 7;

    const int crow = lane >> 2;
    const int cofs = (lane & 3) << 3;

    f32x4 acc[4][4];
    const f32x4 zero = {0.f, 0.f, 0.f, 0.f};
#pragma unroll
    for (int r = 0; r < 4; ++r)
#pragma unroll
        for (int c = 0; c < 4; ++c) acc[r][c] = zero;

    const int wr = (w >> 1) << 6;
    const int wc = (w & 1) << 6;

    for (int k0 = 0; k0 < 1024; k0 += 32) {
#pragma unroll
        for (int c = 0; c < 2; ++c) {
            const int ch  = w + c * 4;
            const int row = ch * 16 + crow;
            gload_lds16(X + (size_t)(m0 + row) * 1024 + k0 + cofs, As + ch * 512 + lane * 8);
            gload_lds16(W + (size_t)(n0 + row) * 1024 + k0 + cofs, Bs + ch * 512 + lane * 8);
        }
        __syncthreads();
        bf16x8 a[4], b[4];
#pragma unroll
        for (int r = 0; r < 4; ++r) a[r] = *(const bf16x8*)(As + (wr + r * 16 + l16) * 32 + quad * 8);
#pragma unroll
        for (int c = 0; c < 4; ++c) b[c] = *(const bf16x8*)(Bs + (wc + c * 16 + l16) * 32 + quad * 8);
#pragma unroll
        for (int r = 0; r < 4; ++r)
#pragma unroll
            for (int c = 0; c < 4; ++c)
                acc[r][c] = __builtin_amdgcn_mfma_f32_16x16x32_bf16(a[r], b[c], acc[r][c], 0, 0, 0);
        __syncthreads();
    }

#pragma unroll
    for (int c = 0; c < 4; ++c) {
        const int n = n0 + wc + c * 16 + l16;
        const float bn = bias[n];
#pragma unroll
        for (int r = 0; r < 4; ++r) {
#pragma unroll
            for (int g = 0; g < 4; ++g) {
                const int m = m0 + wr + r * 16 + quad * 4 + g;
                out[(size_t)m * 1024 + n] = acc[r][c][g] + bn;
            }
        }
    }
}

extern "C" void kernel_launch(void* const* d_in, const int* in_sizes, int n_in,
                              void* d_out, int out_size, void* d_ws, size_t ws_size,
                              hipStream_t stream)
{
    const float* q   = (const float*)d_in[0];
    const float* k   = (const float*)d_in[1];
    const float* v   = (const float*)d_in[2];
    const float* rel = (const float*)d_in[3];
    // d_in[4] = attn_mask: statically causal tril, not read
    const float* wq = (const float*)d_in[5];  const float* bq = (const float*)d_in[6];
    const float* wk = (const float*)d_in[7];  const float* bk = (const float*)d_in[8];
    const float* wv = (const float*)d_in[9];  const float* bv = (const float*)d_in[10];
    const float* wo = (const float*)d_in[11]; const float* bo = (const float*)d_in[12];

    u16* ws = (u16*)d_ws;                 // 96 MB used
    u16* Qw   = ws;
    u16* Kw   = ws + 8388608ULL;
    u16* Vw   = ws + 16777216ULL;
    u16* Ow   = ws + 25165824ULL;
    u16* relb = ws + 33554432ULL;

    // bf16 staging aliases (dead by the time their hosts are written):
    u16* Xqb = Ow;                         // overwritten by attn (after qkv)
    u16* Xkb = relb;                       // overwritten by rel_perm (after qkv)
    u16* Xvb = relb + 8388608ULL;
    u16* Wqb = (u16*)d_out;                // d_out as scratch; out_proj rewrites it
    u16* Wkb = Wqb + 1048576ULL;
    u16* Wvb = Wqb + 2097152ULL;
    u16* Wob = Qw;                         // Qw dead after attn

    // X, W -> bf16
    cvt_bf16_kernel<<<1024, 256, 0, stream>>>(q, Xqb, 1048576);
    cvt_bf16_kernel<<<1024, 256, 0, stream>>>(k, Xkb, 1048576);
    cvt_bf16_kernel<<<1024, 256, 0, stream>>>(v, Xvb, 1048576);
    cvt_bf16_kernel<<<512, 256, 0, stream>>>(wq, Wqb, 131072);
    cvt_bf16_kernel<<<512, 256, 0, stream>>>(wk, Wkb, 131072);
    cvt_bf16_kernel<<<512, 256, 0, stream>>>(wv, Wvb, 131072);

    qkv_proj_kernel<<<1536, 256, 0, stream>>>(Xqb, Xkb, Xvb, Wqb, Wkb, Wvb,
                                              bq, bk, bv, Qw, Kw, Vw);
    rel_perm_kernel<<<4096, 256, 0, stream>>>(rel, relb);    // overwrites Xkb/Xvb (dead)
    attn_kernel<<<512, 512, 0, stream>>>(Qw, Kw, Vw, relb, Ow);   // overwrites Xqb (dead)
    cvt_bf16_kernel<<<512, 256, 0, stream>>>(wo, Wob, 131072);    // into dead Qw region
    out_proj_kernel<<<512, 256, 0, stream>>>(Ow, Wob, bo, (float*)d_out);
}

// Round 4
// 460.490 us; speedup vs baseline: 1.0522x; 1.0522x over previous
//
#include <hip/hip_runtime.h>

// FlashMultiHeadAttention  B=4 S=2048 HIDDEN=1024 H=16 Dh=64 (fp32 I/O)
// r9: break the barrier convoy in attn. r8 doubled occupancy (19.5->38.9%) with
//     zero speedup: waves are barrier-locked 2x/tile, so all waves stall through
//     the same shfl/exp2/LDS-latency phases simultaneously.
//  (a) double-buffered Ks/Vt -> ONE __syncthreads per 64-key tile (waves drift).
//  (b) K/V LDS: stride 64 + XOR chunk swizzle (chunk ^= row&7) on store+read:
//      structurally conflict-free b128 reads (was 9.8M conflict cycles via 72-pad).
//  (c) lrow sum-reduce deferred to epilogue (lane-local partials; alpha is
//      row-uniform) — removes a 4-hop shuffle chain from every tile.
// ws (u16 elems, 96 MB): Qw[0,8M) Kw[8M,16M) Vt[16M,24M) Ow[24M,32M) rel'[32M,48M)
//     aliases: Xq_bf16 = Ow region, Xk/Xv_bf16 = rel' region (rel_perm runs after
//     qkv), Wq/Wk/Wv_bf16 = d_out scratch, Wo_bf16 = Qw region (dead after attn).

#define SEQ 2048
#define NH 16
#define DH 64
#define HID 1024
#define QSCALE 0.18033688011112f   // 0.125 * log2(e)

typedef short bf16x8 __attribute__((ext_vector_type(8)));
typedef float f32x4  __attribute__((ext_vector_type(4)));
typedef unsigned short u16;
typedef unsigned short u16x4 __attribute__((ext_vector_type(4)));
typedef unsigned short u16x8 __attribute__((ext_vector_type(8)));

__device__ __forceinline__ float b2f(u16 u) {
    union { unsigned i; float f; } x; x.i = ((unsigned)u) << 16; return x.f;
}
__device__ __forceinline__ u16 f2b(float f) {
    union { float f; unsigned i; } x; x.f = f;
    unsigned r = x.i + 0x7fffu + ((x.i >> 16) & 1u);
    return (u16)(r >> 16);
}

typedef const __attribute__((address_space(1))) unsigned int guint;
typedef __attribute__((address_space(3))) unsigned int luint;
__device__ __forceinline__ void gload_lds16(const u16* g, u16* l) {
    __builtin_amdgcn_global_load_lds((guint*)g, (luint*)l, 16, 0, 0);
}

// ---------------- fp32 -> bf16 bulk convert (vectorized, grid-stride) ----------------
__global__ __launch_bounds__(256) void cvt_bf16_kernel(
    const float* __restrict__ in, u16* __restrict__ out, int n8)
{
    int i = blockIdx.x * 256 + threadIdx.x;
    const int stride = gridDim.x * 256;
    for (; i < n8; i += stride) {
        f32x4 a = *(const f32x4*)(in + (size_t)i * 8);
        f32x4 b = *(const f32x4*)(in + (size_t)i * 8 + 4);
        u16x8 o;
#pragma unroll
        for (int j = 0; j < 4; ++j) { o[j] = f2b(a[j]); o[j + 4] = f2b(b[j]); }
        *(u16x8*)(out + (size_t)i * 8) = o;
    }
}

// ---------------- rel -> bf16, pre-scaled, permuted to MFMA C-fragment order ----------
// out[b][qt16 (128)][kt64 (32)][lane (64)][nt (4)][g (4)]  where for element (q,k):
//   qt16=q>>4, kt64=k>>6, lane=((q>>2)&3)*16 + (k&15), nt=(k>>4)&3, g=q&3
__global__ __launch_bounds__(256) void rel_perm_kernel(
    const float* __restrict__ rel, u16* __restrict__ out)
{
    __shared__ u16 pl[4096];             // 4 qt16-subtiles x 1024
    const int t   = threadIdx.x;
    const int blk = blockIdx.x;          // 4096 = 4b x 32qc x 32kc
    const int b   = blk >> 10;
    const int qc  = (blk >> 5) & 31;
    const int kc  = blk & 31;
    const int qloc  = t >> 2;            // 0..63
    const int kloc0 = (t & 3) << 4;      // 0,16,32,48

    const float* src = rel + ((size_t)b * SEQ + qc * 64 + qloc) * SEQ + kc * 64 + kloc0;
    const int qt   = qloc >> 4;
    const int quad = (qloc >> 2) & 3;
    const int g    = qloc & 3;
    const int nt   = t & 3;
    u16* dst = pl + qt * 1024 + quad * 256 + nt * 4 + g;
#pragma unroll
    for (int c = 0; c < 4; ++c) {
        f32x4 x = *(const f32x4*)(src + c * 4);
#pragma unroll
        for (int j = 0; j < 4; ++j)
            dst[(c * 4 + j) * 16] = f2b(x[j] * QSCALE);
    }
    __syncthreads();
    const size_t obase = (((size_t)b * 128 + qc * 4) * 32 + kc) * 1024;
#pragma unroll
    for (int q2 = 0; q2 < 4; ++q2)
        *(u16x4*)(out + obase + (size_t)q2 * 32768 + t * 4) =
            *(const u16x4*)(pl + q2 * 1024 + t * 4);
}

// ---------------- QKV projection: bf16 LDS-staged GEMM, Y = X @ W^T + b ----------------
__global__ __launch_bounds__(256) void qkv_proj_kernel(
    const u16* __restrict__ xq, const u16* __restrict__ xk, const u16* __restrict__ xv,
    const u16* __restrict__ wq, const u16* __restrict__ wk, const u16* __restrict__ wv,
    const float* __restrict__ bq, const float* __restrict__ bk, const float* __restrict__ bv,
    u16* __restrict__ Qw, u16* __restrict__ Kw, u16* __restrict__ Vw)
{
    __shared__ __align__(16) u16 As[128 * 32];
    __shared__ __align__(16) u16 Bs[128 * 32];

    const int tid  = threadIdx.x;
    const int w    = tid >> 6;
    const int lane = tid & 63;
    const int l16  = lane & 15;
    const int quad = lane >> 4;

    const int bid = blockIdx.x;
    const int sel = bid >> 9;            // 0=q 1=k 2=v  (512 blocks each)
    const int rem = bid & 511;
    const int tm = rem >> 3, tn = rem & 7;
    const int m0 = tm << 7, n0 = tn << 7;

    const u16* X    = sel == 0 ? xq : (sel == 1 ? xk : xv);
    const u16* W    = sel == 0 ? wq : (sel == 1 ? wk : wv);
    const float* bias = sel == 0 ? bq : (sel == 1 ? bk : bv);

    const int crow = lane >> 2;          // row within chunk 0..15
    const int cofs = (lane & 3) << 3;    // elem offset 0,8,16,24

    f32x4 acc[4][4];
    const f32x4 zero = {0.f, 0.f, 0.f, 0.f};
#pragma unroll
    for (int r = 0; r < 4; ++r)
#pragma unroll
        for (int c = 0; c < 4; ++c) acc[r][c] = zero;

    const int wr = (w >> 1) << 6;
    const int wc = (w & 1) << 6;

    for (int k0 = 0; k0 < 1024; k0 += 32) {
#pragma unroll
        for (int c = 0; c < 2; ++c) {
            const int ch  = w + c * 4;
            const int row = ch * 16 + crow;
            gload_lds16(X + (size_t)(m0 + row) * 1024 + k0 + cofs, As + ch * 512 + lane * 8);
            gload_lds16(W + (size_t)(n0 + row) * 1024 + k0 + cofs, Bs + ch * 512 + lane * 8);
        }
        __syncthreads();
        bf16x8 a[4], b[4];
#pragma unroll
        for (int r = 0; r < 4; ++r) a[r] = *(const bf16x8*)(As + (wr + r * 16 + l16) * 32 + quad * 8);
#pragma unroll
        for (int c = 0; c < 4; ++c) b[c] = *(const bf16x8*)(Bs + (wc + c * 16 + l16) * 32 + quad * 8);
#pragma unroll
        for (int r = 0; r < 4; ++r)
#pragma unroll
            for (int c = 0; c < 4; ++c)
                acc[r][c] = __builtin_amdgcn_mfma_f32_16x16x32_bf16(a[r], b[c], acc[r][c], 0, 0, 0);
        __syncthreads();
    }

    // C layout: col(n)=lane&15, row(m)=quad*4+reg
#pragma unroll
    for (int c = 0; c < 4; ++c) {
        const int n = n0 + wc + c * 16 + l16;
        const float bn = bias[n];
        const int h = n >> 6, d = n & 63;
#pragma unroll
        for (int r = 0; r < 4; ++r) {
#pragma unroll
            for (int g = 0; g < 4; ++g) {
                const int m  = m0 + wr + r * 16 + quad * 4 + g;
                const int b_ = m >> 11, s_ = m & 2047;
                const float val = acc[r][c][g] + bn;
                if (sel == 0)
                    Qw[(((size_t)(b_ * 16 + h)) * 2048 + s_) * 64 + d] = f2b(val * QSCALE);
                else if (sel == 1)
                    Kw[(((size_t)(b_ * 16 + h)) * 2048 + s_) * 64 + d] = f2b(val);
                else
                    Vw[(((size_t)(b_ * 16 + h)) * 64 + d) * 2048 + s_] = f2b(val);  // transposed
            }
        }
    }
}

// swizzled LDS addr for 64-wide u16 rows: 16B chunk index XORed with row&7
#define SWZ(R, C) (((R) << 6) + ((((C) ^ ((R) & 7))) << 3))

// ---------------- Flash attention: 8 waves/block, 16 q/wave, 2 strips/block ----------------
// double-buffered K/V LDS, 1 barrier per tile, swizzled conflict-free layout
__global__ __launch_bounds__(512, 4) void attn_kernel(
    const u16* __restrict__ Qb, const u16* __restrict__ Kb,
    const u16* __restrict__ Vb, const u16* __restrict__ relb,
    u16* __restrict__ Ob)
{
    __shared__ __align__(16) u16 lds[25600];   // Ks[2]:4096 ea | Vt[2]:4096 ea | Pl 8x1152
    const int tid  = threadIdx.x;              // 0..511
    const int w    = tid >> 6;                 // 0..7
    const int lane = tid & 63;
    const int l16  = lane & 15;
    const int quad = lane >> 4;
    u16* Pl = lds + 16384 + w * 1152;          // 16 rows x 72

    const int bh = blockIdx.x & 63;
    const int p  = blockIdx.x >> 6;            // 0..7 strip pair
    const int b  = bh >> 4, h = bh & 15;

    const u16* Qp = Qb + (size_t)bh * SEQ * DH;
    const u16* Kg = Kb + (size_t)bh * SEQ * DH;
    const u16* Vg = Vb + (size_t)bh * DH * SEQ;

    // staging: 512 16B-chunks per tile kind, exactly 1 per thread
    const int r0 = tid >> 3;                   // row 0..63
    const int c0 = tid & 7;                    // chunk 0..7
    const int o0 = c0 << 3;                    // linear elem offset (global src)
    const int sw0 = ((c0 ^ (r0 & 7)) << 3);    // swizzled elem offset (LDS dst)

    for (int sidx = 0; sidx < 2; ++sidx) {
        const int qb  = sidx ? (15 - p) : p;
        const int q0w = qb * 128 + w * 16;     // wave's 16-query window

        // Q A-fragments (persistent; Q pre-scaled by QSCALE)
        bf16x8 qa[2];
#pragma unroll
        for (int ks = 0; ks < 2; ++ks)
            qa[ks] = *(const bf16x8*)(Qp + (size_t)(q0w + l16) * 64 + ks * 32 + quad * 8);

        f32x4 o[4], mrow, lrow;
        const f32x4 zero = {0.f, 0.f, 0.f, 0.f};
        const f32x4 ninf = {-1e30f, -1e30f, -1e30f, -1e30f};
        mrow = ninf; lrow = zero;
#pragma unroll
        for (int dt = 0; dt < 4; ++dt) o[dt] = zero;

        const int ntiles  = qb * 2 + 2;              // staged by the block (always even)
        const int mytiles = qb * 2 + (w >> 2) + 1;   // processed by this wave

        // rel (permuted) base: idx = (b*128+qt)*32768 + kt*1024 + lane*16
        const u16* relW = relb + ((size_t)(b * 128 + (q0w >> 4))) * 32768 + (size_t)lane * 16;

        // prefetch tile 0
        bf16x8 kreg = *(const bf16x8*)(Kg + (size_t)r0 * 64 + o0);
        bf16x8 vreg = *(const bf16x8*)(Vg + (size_t)r0 * 2048 + o0);
        bf16x8 rr0 = *(const bf16x8*)(relW);
        bf16x8 rr1 = *(const bf16x8*)(relW + 8);

        for (int kt = 0; kt < ntiles; ++kt) {
            const int k0 = kt << 6;
            u16* Ksb = lds + ((kt & 1) << 12);
            u16* Vtb = lds + 8192 + ((kt & 1) << 12);
            // regs -> LDS buf[kt&1] (swizzled)
            *(bf16x8*)(Ksb + r0 * 64 + sw0) = kreg;
            *(bf16x8*)(Vtb + r0 * 64 + sw0) = vreg;

            const bool act = kt < mytiles;
            // s-init from prefetched rel regs (pure VALU, before barrier)
            f32x4 s[4];
            if (act) {
#pragma unroll
                for (int nt = 0; nt < 4; ++nt)
#pragma unroll
                    for (int g = 0; g < 4; ++g)
                        s[nt][g] = b2f((u16)((nt < 2 ? rr0 : rr1)[(nt & 1) * 4 + g]));
            }

            // issue next tile's global loads (latency hidden under compute)
            const int ktn = (kt + 1 < ntiles) ? kt + 1 : kt;
            const int kn  = ktn << 6;
            kreg = *(const bf16x8*)(Kg + (size_t)(kn + r0) * 64 + o0);
            vreg = *(const bf16x8*)(Vg + (size_t)r0 * 2048 + kn + o0);
            rr0  = *(const bf16x8*)(relW + (size_t)ktn * 1024);
            rr1  = *(const bf16x8*)(relW + (size_t)ktn * 1024 + 8);

            __syncthreads();   // single barrier: buf[kt&1] ready; WAR separated by next barrier

            if (act) {
                // ---- scores: C init = rel' (done above), MFMA adds scaled QK^T ----
#pragma unroll
                for (int nt = 0; nt < 4; ++nt) {
                    const int R = nt * 16 + l16;
                    bf16x8 kb0 = *(const bf16x8*)(Ksb + SWZ(R, quad));
                    bf16x8 kb1 = *(const bf16x8*)(Ksb + SWZ(R, 4 | quad));
                    s[nt] = __builtin_amdgcn_mfma_f32_16x16x32_bf16(qa[0], kb0, s[nt], 0, 0, 0);
                    s[nt] = __builtin_amdgcn_mfma_f32_16x16x32_bf16(qa[1], kb1, s[nt], 0, 0, 0);
                }
                // ---- causal mask (diagonal tile only) ----
                if (kt == mytiles - 1) {
#pragma unroll
                    for (int nt = 0; nt < 4; ++nt)
#pragma unroll
                        for (int g = 0; g < 4; ++g) {
                            const int q = q0w + quad * 4 + g;
                            const int k = k0 + nt * 16 + l16;
                            if (k > q) s[nt][g] = -1e30f;
                        }
                }
                // ---- online softmax (exp2 domain); row-sum deferred to epilogue ----
                {
                    f32x4 t;
#pragma unroll
                    for (int g = 0; g < 4; ++g)
                        t[g] = fmaxf(fmaxf(s[0][g], s[1][g]), fmaxf(s[2][g], s[3][g]));
#pragma unroll
                    for (int off = 1; off < 16; off <<= 1)
#pragma unroll
                        for (int g = 0; g < 4; ++g)
                            t[g] = fmaxf(t[g], __shfl_xor(t[g], off, 64));
                    f32x4 mn, alpha;
#pragma unroll
                    for (int g = 0; g < 4; ++g) {
                        mn[g] = fmaxf(mrow[g], t[g]);
                        alpha[g] = __builtin_amdgcn_exp2f(mrow[g] - mn[g]);
                    }
                    mrow = mn;
#pragma unroll
                    for (int dt = 0; dt < 4; ++dt)
#pragma unroll
                        for (int g = 0; g < 4; ++g) o[dt][g] *= alpha[g];
#pragma unroll
                    for (int nt = 0; nt < 4; ++nt)
#pragma unroll
                        for (int g = 0; g < 4; ++g)
                            s[nt][g] = __builtin_amdgcn_exp2f(s[nt][g] - mn[g]);
                    // lane-local partial row-sum (alpha is row-uniform -> consistent)
#pragma unroll
                    for (int g = 0; g < 4; ++g)
                        lrow[g] = lrow[g] * alpha[g]
                                + ((s[0][g] + s[1][g]) + (s[2][g] + s[3][g]));
                }
                // ---- P -> bf16 -> per-wave LDS ----
#pragma unroll
                for (int nt = 0; nt < 4; ++nt)
#pragma unroll
                    for (int g = 0; g < 4; ++g)
                        Pl[(quad * 4 + g) * 72 + nt * 16 + l16] = f2b(s[nt][g]);
                // ---- PV ----
                bf16x8 pa[2];
#pragma unroll
                for (int ks = 0; ks < 2; ++ks)
                    pa[ks] = *(const bf16x8*)(Pl + l16 * 72 + ks * 32 + quad * 8);
#pragma unroll
                for (int dt = 0; dt < 4; ++dt) {
                    const int R = dt * 16 + l16;
                    bf16x8 vb0 = *(const bf16x8*)(Vtb + SWZ(R, quad));
                    bf16x8 vb1 = *(const bf16x8*)(Vtb + SWZ(R, 4 | quad));
                    o[dt] = __builtin_amdgcn_mfma_f32_16x16x32_bf16(pa[0], vb0, o[dt], 0, 0, 0);
                    o[dt] = __builtin_amdgcn_mfma_f32_16x16x32_bf16(pa[1], vb1, o[dt], 0, 0, 0);
                }
            }
        }

        // ---- epilogue: reduce lrow across the 16-lane k-groups, then store ----
#pragma unroll
        for (int off = 1; off < 16; off <<= 1)
#pragma unroll
            for (int g = 0; g < 4; ++g)
                lrow[g] += __shfl_xor(lrow[g], off, 64);
        {
            f32x4 linv;
#pragma unroll
            for (int g = 0; g < 4; ++g) linv[g] = 1.0f / lrow[g];
#pragma unroll
            for (int dt = 0; dt < 4; ++dt)
#pragma unroll
                for (int g = 0; g < 4; ++g)
                    Pl[(quad * 4 + g) * 72 + dt * 16 + l16] = f2b(o[dt][g] * linv[g]);
        }
#pragma unroll
        for (int pp = 0; pp < 2; ++pp) {
            const int c = lane + pp * 64;
            const int row = c >> 3, col = (c & 7) << 3;
            bf16x8 t = *(const bf16x8*)(Pl + row * 72 + col);
            *(bf16x8*)(Ob + ((size_t)b * SEQ + q0w + row) * HID + h * DH + col) = t;
        }
    }
}

// ---------------- Output projection: bf16 LDS-staged GEMM, out = O @ Wout^T + bout ----------------
__global__ __launch_bounds__(256) void out_proj_kernel(
    const u16* __restrict__ X, const u16* __restrict__ W,
    const float* __restrict__ bias, float* __restrict__ out)
{
    __shared__ __align__(16) u16 As[128 * 32];
    __shared__ __align__(16) u16 Bs[128 * 32];

    const int tid  = threadIdx.x;
    const int w    = tid >> 6;
    const int lane = tid & 63;
    const int l16  = lane & 15;
    const int quad = lane >> 4;

    const int bid = blockIdx.x;
    const int tm = bid >> 3, tn = bid & 7;
    const int m0 = tm << 7, n0 = tn << 7;

    const int crow = lane >> 2;
    const int cofs = (lane & 3) << 3;

    f32x4 acc[4][4];
    const f32x4 zero = {0.f, 0.f, 0.f, 0.f};
#pragma unroll
    for (int r = 0; r < 4; ++r)
#pragma unroll
        for (int c = 0; c < 4; ++c) acc[r][c] = zero;

    const int wr = (w >> 1) << 6;
    const int wc = (w & 1) << 6;

    for (int k0 = 0; k0 < 1024; k0 += 32) {
#pragma unroll
        for (int c = 0; c < 2; ++c) {
            const int ch  = w + c * 4;
            const int row = ch * 16 + crow;
            gload_lds16(X + (size_t)(m0 + row) * 1024 + k0 + cofs, As + ch * 512 + lane * 8);
            gload_lds16(W + (size_t)(n0 + row) * 1024 + k0 + cofs, Bs + ch * 512 + lane * 8);
        }
        __syncthreads();
        bf16x8 a[4], b[4];
#pragma unroll
        for (int r = 0; r < 4; ++r) a[r] = *(const bf16x8*)(As + (wr + r * 16 + l16) * 32 + quad * 8);
#pragma unroll
        for (int c = 0; c < 4; ++c) b[c] = *(const bf16x8*)(Bs + (wc + c * 16 + l16) * 32 + quad * 8);
#pragma unroll
        for (int r = 0; r < 4; ++r)
#pragma unroll
            for (int c = 0; c < 4; ++c)
                acc[r][c] = __builtin_amdgcn_mfma_f32_16x16x32_bf16(a[r], b[c], acc[r][c], 0, 0, 0);
        __syncthreads();
    }

#pragma unroll
    for (int c = 0; c < 4; ++c) {
        const int n = n0 + wc + c * 16 + l16;
        const float bn = bias[n];
#pragma unroll
        for (int r = 0; r < 4; ++r) {
#pragma unroll
            for (int g = 0; g < 4; ++g) {
                const int m = m0 + wr + r * 16 + quad * 4 + g;
                out[(size_t)m * 1024 + n] = acc[r][c][g] + bn;
            }
        }
    }
}

extern "C" void kernel_launch(void* const* d_in, const int* in_sizes, int n_in,
                              void* d_out, int out_size, void* d_ws, size_t ws_size,
                              hipStream_t stream)
{
    const float* q   = (const float*)d_in[0];
    const float* k   = (const float*)d_in[1];
    const float* v   = (const float*)d_in[2];
    const float* rel = (const float*)d_in[3];
    // d_in[4] = attn_mask: statically causal tril, not read
    const float* wq = (const float*)d_in[5];  const float* bq = (const float*)d_in[6];
    const float* wk = (const float*)d_in[7];  const float* bk = (const float*)d_in[8];
    const float* wv = (const float*)d_in[9];  const float* bv = (const float*)d_in[10];
    const float* wo = (const float*)d_in[11]; const float* bo = (const float*)d_in[12];

    u16* ws = (u16*)d_ws;                 // 96 MB used
    u16* Qw   = ws;
    u16* Kw   = ws + 8388608ULL;
    u16* Vw   = ws + 16777216ULL;
    u16* Ow   = ws + 25165824ULL;
    u16* relb = ws + 33554432ULL;

    // bf16 staging aliases (dead by the time their hosts are written):
    u16* Xqb = Ow;                         // overwritten by attn (after qkv)
    u16* Xkb = relb;                       // overwritten by rel_perm (after qkv)
    u16* Xvb = relb + 8388608ULL;
    u16* Wqb = (u16*)d_out;                // d_out as scratch; out_proj rewrites it
    u16* Wkb = Wqb + 1048576ULL;
    u16* Wvb = Wqb + 2097152ULL;
    u16* Wob = Qw;                         // Qw dead after attn

    // X, W -> bf16
    cvt_bf16_kernel<<<1024, 256, 0, stream>>>(q, Xqb, 1048576);
    cvt_bf16_kernel<<<1024, 256, 0, stream>>>(k, Xkb, 1048576);
    cvt_bf16_kernel<<<1024, 256, 0, stream>>>(v, Xvb, 1048576);
    cvt_bf16_kernel<<<512, 256, 0, stream>>>(wq, Wqb, 131072);
    cvt_bf16_kernel<<<512, 256, 0, stream>>>(wk, Wkb, 131072);
    cvt_bf16_kernel<<<512, 256, 0, stream>>>(wv, Wvb, 131072);

    qkv_proj_kernel<<<1536, 256, 0, stream>>>(Xqb, Xkb, Xvb, Wqb, Wkb, Wvb,
                                              bq, bk, bv, Qw, Kw, Vw);
    rel_perm_kernel<<<4096, 256, 0, stream>>>(rel, relb);    // overwrites Xkb/Xvb (dead)
    attn_kernel<<<512, 512, 0, stream>>>(Qw, Kw, Vw, relb, Ow);   // overwrites Xqb (dead)
    cvt_bf16_kernel<<<512, 256, 0, stream>>>(wo, Wob, 131072);    // into dead Qw region
    out_proj_kernel<<<512, 256, 0, stream>>>(Ow, Wob, bo, (float*)d_out);
}

// Round 5
// 452.845 us; speedup vs baseline: 1.0699x; 1.0169x over previous
//
#include <hip/hip_runtime.h>

// FlashMultiHeadAttention  B=4 S=2048 HIDDEN=1024 H=16 Dh=64 (fp32 I/O)
// r10: qkv/out_proj GEMM fixes (r9 counters: 6.3M bank-conflict cycles, FETCH
//      200MB vs 54MB compulsory, MfmaUtil 16%).
//  (a) LDS fragment reads were 8-way bank-conflicted (64B rows: even/odd l16
//      lanes pile on 2 bank-groups). Fix via both-sides XOR swizzle (rule 21:
//      gload_lds writes linearly -> pre-swizzle the GLOBAL source chunk
//      (l&3)^((l>>3)&3), read back at chunk quad^((R>>1)&3)). 16 consecutive
//      rows now cover all 8 {bank-half x slot} combos -> 2-way = free.
//  (b) XCD-aware bijective block remap (1536%8==0, 512%8==0): consecutive
//      logical blocks (sharing X panels) land on the SAME XCD's L2.
// ws (u16 elems, 96 MB): Qw[0,8M) Kw[8M,16M) Vt[16M,24M) Ow[24M,32M) rel'[32M,48M)
//     aliases: Xq_bf16 = Ow region, Xk/Xv_bf16 = rel' region, Wq/Wk/Wv_bf16 =
//     d_out scratch, Wo_bf16 = Qw region (dead after attn).

#define SEQ 2048
#define NH 16
#define DH 64
#define HID 1024
#define QSCALE 0.18033688011112f   // 0.125 * log2(e)

typedef short bf16x8 __attribute__((ext_vector_type(8)));
typedef float f32x4  __attribute__((ext_vector_type(4)));
typedef unsigned short u16;
typedef unsigned short u16x4 __attribute__((ext_vector_type(4)));
typedef unsigned short u16x8 __attribute__((ext_vector_type(8)));

__device__ __forceinline__ float b2f(u16 u) {
    union { unsigned i; float f; } x; x.i = ((unsigned)u) << 16; return x.f;
}
__device__ __forceinline__ u16 f2b(float f) {
    union { float f; unsigned i; } x; x.f = f;
    unsigned r = x.i + 0x7fffu + ((x.i >> 16) & 1u);
    return (u16)(r >> 16);
}

typedef const __attribute__((address_space(1))) unsigned int guint;
typedef __attribute__((address_space(3))) unsigned int luint;
__device__ __forceinline__ void gload_lds16(const u16* g, u16* l) {
    __builtin_amdgcn_global_load_lds((guint*)g, (luint*)l, 16, 0, 0);
}

// ---------------- fp32 -> bf16 bulk convert (vectorized, grid-stride) ----------------
__global__ __launch_bounds__(256) void cvt_bf16_kernel(
    const float* __restrict__ in, u16* __restrict__ out, int n8)
{
    int i = blockIdx.x * 256 + threadIdx.x;
    const int stride = gridDim.x * 256;
    for (; i < n8; i += stride) {
        f32x4 a = *(const f32x4*)(in + (size_t)i * 8);
        f32x4 b = *(const f32x4*)(in + (size_t)i * 8 + 4);
        u16x8 o;
#pragma unroll
        for (int j = 0; j < 4; ++j) { o[j] = f2b(a[j]); o[j + 4] = f2b(b[j]); }
        *(u16x8*)(out + (size_t)i * 8) = o;
    }
}

// ---------------- rel -> bf16, pre-scaled, permuted to MFMA C-fragment order ----------
// out[b][qt16 (128)][kt64 (32)][lane (64)][nt (4)][g (4)]  where for element (q,k):
//   qt16=q>>4, kt64=k>>6, lane=((q>>2)&3)*16 + (k&15), nt=(k>>4)&3, g=q&3
__global__ __launch_bounds__(256) void rel_perm_kernel(
    const float* __restrict__ rel, u16* __restrict__ out)
{
    __shared__ u16 pl[4096];             // 4 qt16-subtiles x 1024
    const int t   = threadIdx.x;
    const int blk = blockIdx.x;          // 4096 = 4b x 32qc x 32kc
    const int b   = blk >> 10;
    const int qc  = (blk >> 5) & 31;
    const int kc  = blk & 31;
    const int qloc  = t >> 2;            // 0..63
    const int kloc0 = (t & 3) << 4;      // 0,16,32,48

    const float* src = rel + ((size_t)b * SEQ + qc * 64 + qloc) * SEQ + kc * 64 + kloc0;
    const int qt   = qloc >> 4;
    const int quad = (qloc >> 2) & 3;
    const int g    = qloc & 3;
    const int nt   = t & 3;
    u16* dst = pl + qt * 1024 + quad * 256 + nt * 4 + g;
#pragma unroll
    for (int c = 0; c < 4; ++c) {
        f32x4 x = *(const f32x4*)(src + c * 4);
#pragma unroll
        for (int j = 0; j < 4; ++j)
            dst[(c * 4 + j) * 16] = f2b(x[j] * QSCALE);
    }
    __syncthreads();
    const size_t obase = (((size_t)b * 128 + qc * 4) * 32 + kc) * 1024;
#pragma unroll
    for (int q2 = 0; q2 < 4; ++q2)
        *(u16x4*)(out + obase + (size_t)q2 * 32768 + t * 4) =
            *(const u16x4*)(pl + q2 * 1024 + t * 4);
}

// swizzled chunk offset within a 32-elem (64B) LDS row, for row R, chunk c (0..3):
//   elem_off = ((c ^ ((R>>1)&3)) << 3)
#define GSWZ(R, C) (((R) << 5) + ((((C) ^ (((R) >> 1) & 3))) << 3))

// ---------------- QKV projection: bf16 LDS-staged GEMM, Y = X @ W^T + b ----------------
__global__ __launch_bounds__(256) void qkv_proj_kernel(
    const u16* __restrict__ xq, const u16* __restrict__ xk, const u16* __restrict__ xv,
    const u16* __restrict__ wq, const u16* __restrict__ wk, const u16* __restrict__ wv,
    const float* __restrict__ bq, const float* __restrict__ bk, const float* __restrict__ bv,
    u16* __restrict__ Qw, u16* __restrict__ Kw, u16* __restrict__ Vw)
{
    __shared__ __align__(16) u16 As[128 * 32];
    __shared__ __align__(16) u16 Bs[128 * 32];

    const int tid  = threadIdx.x;
    const int w    = tid >> 6;
    const int lane = tid & 63;
    const int l16  = lane & 15;
    const int quad = lane >> 4;

    // XCD-aware bijective remap: 1536 blocks, 8 XCDs, 192 contiguous each
    const int lbid = ((blockIdx.x & 7) * 192) + (blockIdx.x >> 3);
    const int sel = lbid >> 9;           // 0=q 1=k 2=v  (512 blocks each)
    const int rem = lbid & 511;
    const int tm = rem >> 3, tn = rem & 7;
    const int m0 = tm << 7, n0 = tn << 7;

    const u16* X    = sel == 0 ? xq : (sel == 1 ? xk : xv);
    const u16* W    = sel == 0 ? wq : (sel == 1 ? wk : wv);
    const float* bias = sel == 0 ? bq : (sel == 1 ? bk : bv);

    const int crow = lane >> 2;                          // row within chunk 0..15
    // pre-swizzled GLOBAL chunk: lane l writes LDS chunk l&3, so it must fetch
    // global chunk (l&3) ^ s(row), s(row) = (row>>1)&3 = (l>>3)&3
    const int csw  = (((lane & 3) ^ ((lane >> 3) & 3)) << 3);

    f32x4 acc[4][4];
    const f32x4 zero = {0.f, 0.f, 0.f, 0.f};
#pragma unroll
    for (int r = 0; r < 4; ++r)
#pragma unroll
        for (int c = 0; c < 4; ++c) acc[r][c] = zero;

    const int wr = (w >> 1) << 6;
    const int wc = (w & 1) << 6;

    for (int k0 = 0; k0 < 1024; k0 += 32) {
#pragma unroll
        for (int c = 0; c < 2; ++c) {
            const int ch  = w + c * 4;
            const int row = ch * 16 + crow;
            gload_lds16(X + (size_t)(m0 + row) * 1024 + k0 + csw, As + ch * 512 + lane * 8);
            gload_lds16(W + (size_t)(n0 + row) * 1024 + k0 + csw, Bs + ch * 512 + lane * 8);
        }
        __syncthreads();
        bf16x8 a[4], b[4];
#pragma unroll
        for (int r = 0; r < 4; ++r) {
            const int R = wr + r * 16 + l16;
            a[r] = *(const bf16x8*)(As + GSWZ(R, quad));
        }
#pragma unroll
        for (int c = 0; c < 4; ++c) {
            const int R = wc + c * 16 + l16;
            b[c] = *(const bf16x8*)(Bs + GSWZ(R, quad));
        }
#pragma unroll
        for (int r = 0; r < 4; ++r)
#pragma unroll
            for (int c = 0; c < 4; ++c)
                acc[r][c] = __builtin_amdgcn_mfma_f32_16x16x32_bf16(a[r], b[c], acc[r][c], 0, 0, 0);
        __syncthreads();
    }

    // C layout: col(n)=lane&15, row(m)=quad*4+reg
#pragma unroll
    for (int c = 0; c < 4; ++c) {
        const int n = n0 + wc + c * 16 + l16;
        const float bn = bias[n];
        const int h = n >> 6, d = n & 63;
#pragma unroll
        for (int r = 0; r < 4; ++r) {
#pragma unroll
            for (int g = 0; g < 4; ++g) {
                const int m  = m0 + wr + r * 16 + quad * 4 + g;
                const int b_ = m >> 11, s_ = m & 2047;
                const float val = acc[r][c][g] + bn;
                if (sel == 0)
                    Qw[(((size_t)(b_ * 16 + h)) * 2048 + s_) * 64 + d] = f2b(val * QSCALE);
                else if (sel == 1)
                    Kw[(((size_t)(b_ * 16 + h)) * 2048 + s_) * 64 + d] = f2b(val);
                else
                    Vw[(((size_t)(b_ * 16 + h)) * 64 + d) * 2048 + s_] = f2b(val);  // transposed
            }
        }
    }
}

// swizzled LDS addr for 64-wide u16 rows: 16B chunk index XORed with row&7
#define SWZ(R, C) (((R) << 6) + ((((C) ^ ((R) & 7))) << 3))

// ---------------- Flash attention: 8 waves/block, 16 q/wave, 2 strips/block ----------------
// double-buffered K/V LDS, 1 barrier per tile, swizzled conflict-free layout
__global__ __launch_bounds__(512, 4) void attn_kernel(
    const u16* __restrict__ Qb, const u16* __restrict__ Kb,
    const u16* __restrict__ Vb, const u16* __restrict__ relb,
    u16* __restrict__ Ob)
{
    __shared__ __align__(16) u16 lds[25600];   // Ks[2]:4096 ea | Vt[2]:4096 ea | Pl 8x1152
    const int tid  = threadIdx.x;              // 0..511
    const int w    = tid >> 6;                 // 0..7
    const int lane = tid & 63;
    const int l16  = lane & 15;
    const int quad = lane >> 4;
    u16* Pl = lds + 16384 + w * 1152;          // 16 rows x 72

    const int bh = blockIdx.x & 63;
    const int p  = blockIdx.x >> 6;            // 0..7 strip pair
    const int b  = bh >> 4, h = bh & 15;

    const u16* Qp = Qb + (size_t)bh * SEQ * DH;
    const u16* Kg = Kb + (size_t)bh * SEQ * DH;
    const u16* Vg = Vb + (size_t)bh * DH * SEQ;

    // staging: 512 16B-chunks per tile kind, exactly 1 per thread
    const int r0 = tid >> 3;                   // row 0..63
    const int c0 = tid & 7;                    // chunk 0..7
    const int o0 = c0 << 3;                    // linear elem offset (global src)
    const int sw0 = ((c0 ^ (r0 & 7)) << 3);    // swizzled elem offset (LDS dst)

    for (int sidx = 0; sidx < 2; ++sidx) {
        const int qb  = sidx ? (15 - p) : p;
        const int q0w = qb * 128 + w * 16;     // wave's 16-query window

        // Q A-fragments (persistent; Q pre-scaled by QSCALE)
        bf16x8 qa[2];
#pragma unroll
        for (int ks = 0; ks < 2; ++ks)
            qa[ks] = *(const bf16x8*)(Qp + (size_t)(q0w + l16) * 64 + ks * 32 + quad * 8);

        f32x4 o[4], mrow, lrow;
        const f32x4 zero = {0.f, 0.f, 0.f, 0.f};
        const f32x4 ninf = {-1e30f, -1e30f, -1e30f, -1e30f};
        mrow = ninf; lrow = zero;
#pragma unroll
        for (int dt = 0; dt < 4; ++dt) o[dt] = zero;

        const int ntiles  = qb * 2 + 2;              // staged by the block (always even)
        const int mytiles = qb * 2 + (w >> 2) + 1;   // processed by this wave

        // rel (permuted) base: idx = (b*128+qt)*32768 + kt*1024 + lane*16
        const u16* relW = relb + ((size_t)(b * 128 + (q0w >> 4))) * 32768 + (size_t)lane * 16;

        // prefetch tile 0
        bf16x8 kreg = *(const bf16x8*)(Kg + (size_t)r0 * 64 + o0);
        bf16x8 vreg = *(const bf16x8*)(Vg + (size_t)r0 * 2048 + o0);
        bf16x8 rr0 = *(const bf16x8*)(relW);
        bf16x8 rr1 = *(const bf16x8*)(relW + 8);

        for (int kt = 0; kt < ntiles; ++kt) {
            const int k0 = kt << 6;
            u16* Ksb = lds + ((kt & 1) << 12);
            u16* Vtb = lds + 8192 + ((kt & 1) << 12);
            // regs -> LDS buf[kt&1] (swizzled)
            *(bf16x8*)(Ksb + r0 * 64 + sw0) = kreg;
            *(bf16x8*)(Vtb + r0 * 64 + sw0) = vreg;

            const bool act = kt < mytiles;
            // s-init from prefetched rel regs (pure VALU, before barrier)
            f32x4 s[4];
            if (act) {
#pragma unroll
                for (int nt = 0; nt < 4; ++nt)
#pragma unroll
                    for (int g = 0; g < 4; ++g)
                        s[nt][g] = b2f((u16)((nt < 2 ? rr0 : rr1)[(nt & 1) * 4 + g]));
            }

            // issue next tile's global loads (latency hidden under compute)
            const int ktn = (kt + 1 < ntiles) ? kt + 1 : kt;
            const int kn  = ktn << 6;
            kreg = *(const bf16x8*)(Kg + (size_t)(kn + r0) * 64 + o0);
            vreg = *(const bf16x8*)(Vg + (size_t)r0 * 2048 + kn + o0);
            rr0  = *(const bf16x8*)(relW + (size_t)ktn * 1024);
            rr1  = *(const bf16x8*)(relW + (size_t)ktn * 1024 + 8);

            __syncthreads();   // single barrier: buf[kt&1] ready; WAR separated by next barrier

            if (act) {
                // ---- scores: C init = rel' (done above), MFMA adds scaled QK^T ----
#pragma unroll
                for (int nt = 0; nt < 4; ++nt) {
                    const int R = nt * 16 + l16;
                    bf16x8 kb0 = *(const bf16x8*)(Ksb + SWZ(R, quad));
                    bf16x8 kb1 = *(const bf16x8*)(Ksb + SWZ(R, 4 | quad));
                    s[nt] = __builtin_amdgcn_mfma_f32_16x16x32_bf16(qa[0], kb0, s[nt], 0, 0, 0);
                    s[nt] = __builtin_amdgcn_mfma_f32_16x16x32_bf16(qa[1], kb1, s[nt], 0, 0, 0);
                }
                // ---- causal mask (diagonal tile only) ----
                if (kt == mytiles - 1) {
#pragma unroll
                    for (int nt = 0; nt < 4; ++nt)
#pragma unroll
                        for (int g = 0; g < 4; ++g) {
                            const int q = q0w + quad * 4 + g;
                            const int k = k0 + nt * 16 + l16;
                            if (k > q) s[nt][g] = -1e30f;
                        }
                }
                // ---- online softmax (exp2 domain); row-sum deferred to epilogue ----
                {
                    f32x4 t;
#pragma unroll
                    for (int g = 0; g < 4; ++g)
                        t[g] = fmaxf(fmaxf(s[0][g], s[1][g]), fmaxf(s[2][g], s[3][g]));
#pragma unroll
                    for (int off = 1; off < 16; off <<= 1)
#pragma unroll
                        for (int g = 0; g < 4; ++g)
                            t[g] = fmaxf(t[g], __shfl_xor(t[g], off, 64));
                    f32x4 mn, alpha;
#pragma unroll
                    for (int g = 0; g < 4; ++g) {
                        mn[g] = fmaxf(mrow[g], t[g]);
                        alpha[g] = __builtin_amdgcn_exp2f(mrow[g] - mn[g]);
                    }
                    mrow = mn;
#pragma unroll
                    for (int dt = 0; dt < 4; ++dt)
#pragma unroll
                        for (int g = 0; g < 4; ++g) o[dt][g] *= alpha[g];
#pragma unroll
                    for (int nt = 0; nt < 4; ++nt)
#pragma unroll
                        for (int g = 0; g < 4; ++g)
                            s[nt][g] = __builtin_amdgcn_exp2f(s[nt][g] - mn[g]);
                    // lane-local partial row-sum (alpha is row-uniform -> consistent)
#pragma unroll
                    for (int g = 0; g < 4; ++g)
                        lrow[g] = lrow[g] * alpha[g]
                                + ((s[0][g] + s[1][g]) + (s[2][g] + s[3][g]));
                }
                // ---- P -> bf16 -> per-wave LDS ----
#pragma unroll
                for (int nt = 0; nt < 4; ++nt)
#pragma unroll
                    for (int g = 0; g < 4; ++g)
                        Pl[(quad * 4 + g) * 72 + nt * 16 + l16] = f2b(s[nt][g]);
                // ---- PV ----
                bf16x8 pa[2];
#pragma unroll
                for (int ks = 0; ks < 2; ++ks)
                    pa[ks] = *(const bf16x8*)(Pl + l16 * 72 + ks * 32 + quad * 8);
#pragma unroll
                for (int dt = 0; dt < 4; ++dt) {
                    const int R = dt * 16 + l16;
                    bf16x8 vb0 = *(const bf16x8*)(Vtb + SWZ(R, quad));
                    bf16x8 vb1 = *(const bf16x8*)(Vtb + SWZ(R, 4 | quad));
                    o[dt] = __builtin_amdgcn_mfma_f32_16x16x32_bf16(pa[0], vb0, o[dt], 0, 0, 0);
                    o[dt] = __builtin_amdgcn_mfma_f32_16x16x32_bf16(pa[1], vb1, o[dt], 0, 0, 0);
                }
            }
        }

        // ---- epilogue: reduce lrow across the 16-lane k-groups, then store ----
#pragma unroll
        for (int off = 1; off < 16; off <<= 1)
#pragma unroll
            for (int g = 0; g < 4; ++g)
                lrow[g] += __shfl_xor(lrow[g], off, 64);
        {
            f32x4 linv;
#pragma unroll
            for (int g = 0; g < 4; ++g) linv[g] = 1.0f / lrow[g];
#pragma unroll
            for (int dt = 0; dt < 4; ++dt)
#pragma unroll
                for (int g = 0; g < 4; ++g)
                    Pl[(quad * 4 + g) * 72 + dt * 16 + l16] = f2b(o[dt][g] * linv[g]);
        }
#pragma unroll
        for (int pp = 0; pp < 2; ++pp) {
            const int c = lane + pp * 64;
            const int row = c >> 3, col = (c & 7) << 3;
            bf16x8 t = *(const bf16x8*)(Pl + row * 72 + col);
            *(bf16x8*)(Ob + ((size_t)b * SEQ + q0w + row) * HID + h * DH + col) = t;
        }
    }
}

// ---------------- Output projection: bf16 LDS-staged GEMM, out = O @ Wout^T + bout ----------------
__global__ __launch_bounds__(256) void out_proj_kernel(
    const u16* __restrict__ X, const u16* __restrict__ W,
    const float* __restrict__ bias, float* __restrict__ out)
{
    __shared__ __align__(16) u16 As[128 * 32];
    __shared__ __align__(16) u16 Bs[128 * 32];

    const int tid  = threadIdx.x;
    const int w    = tid >> 6;
    const int lane = tid & 63;
    const int l16  = lane & 15;
    const int quad = lane >> 4;

    // XCD-aware bijective remap: 512 blocks, 64 contiguous per XCD
    const int lbid = ((blockIdx.x & 7) * 64) + (blockIdx.x >> 3);
    const int tm = lbid >> 3, tn = lbid & 7;
    const int m0 = tm << 7, n0 = tn << 7;

    const int crow = lane >> 2;
    const int csw  = (((lane & 3) ^ ((lane >> 3) & 3)) << 3);

    f32x4 acc[4][4];
    const f32x4 zero = {0.f, 0.f, 0.f, 0.f};
#pragma unroll
    for (int r = 0; r < 4; ++r)
#pragma unroll
        for (int c = 0; c < 4; ++c) acc[r][c] = zero;

    const int wr = (w >> 1) << 6;
    const int wc = (w & 1) << 6;

    for (int k0 = 0; k0 < 1024; k0 += 32) {
#pragma unroll
        for (int c = 0; c < 2; ++c) {
            const int ch  = w + c * 4;
            const int row = ch * 16 + crow;
            gload_lds16(X + (size_t)(m0 + row) * 1024 + k0 + csw, As + ch * 512 + lane * 8);
            gload_lds16(W + (size_t)(n0 + row) * 1024 + k0 + csw, Bs + ch * 512 + lane * 8);
        }
        __syncthreads();
        bf16x8 a[4], b[4];
#pragma unroll
        for (int r = 0; r < 4; ++r) {
            const int R = wr + r * 16 + l16;
            a[r] = *(const bf16x8*)(As + GSWZ(R, quad));
        }
#pragma unroll
        for (int c = 0; c < 4; ++c) {
            const int R = wc + c * 16 + l16;
            b[c] = *(const bf16x8*)(Bs + GSWZ(R, quad));
        }
#pragma unroll
        for (int r = 0; r < 4; ++r)
#pragma unroll
            for (int c = 0; c < 4; ++c)
                acc[r][c] = __builtin_amdgcn_mfma_f32_16x16x32_bf16(a[r], b[c], acc[r][c], 0, 0, 0);
        __syncthreads();
    }

#pragma unroll
    for (int c = 0; c < 4; ++c) {
        const int n = n0 + wc + c * 16 + l16;
        const float bn = bias[n];
#pragma unroll
        for (int r = 0; r < 4; ++r) {
#pragma unroll
            for (int g = 0; g < 4; ++g) {
                const int m = m0 + wr + r * 16 + quad * 4 + g;
                out[(size_t)m * 1024 + n] = acc[r][c][g] + bn;
            }
        }
    }
}

extern "C" void kernel_launch(void* const* d_in, const int* in_sizes, int n_in,
                              void* d_out, int out_size, void* d_ws, size_t ws_size,
                              hipStream_t stream)
{
    const float* q   = (const float*)d_in[0];
    const float* k   = (const float*)d_in[1];
    const float* v   = (const float*)d_in[2];
    const float* rel = (const float*)d_in[3];
    // d_in[4] = attn_mask: statically causal tril, not read
    const float* wq = (const float*)d_in[5];  const float* bq = (const float*)d_in[6];
    const float* wk = (const float*)d_in[7];  const float* bk = (const float*)d_in[8];
    const float* wv = (const float*)d_in[9];  const float* bv = (const float*)d_in[10];
    const float* wo = (const float*)d_in[11]; const float* bo = (const float*)d_in[12];

    u16* ws = (u16*)d_ws;                 // 96 MB used
    u16* Qw   = ws;
    u16* Kw   = ws + 8388608ULL;
    u16* Vw   = ws + 16777216ULL;
    u16* Ow   = ws + 25165824ULL;
    u16* relb = ws + 33554432ULL;

    // bf16 staging aliases (dead by the time their hosts are written):
    u16* Xqb = Ow;                         // overwritten by attn (after qkv)
    u16* Xkb = relb;                       // overwritten by rel_perm (after qkv)
    u16* Xvb = relb + 8388608ULL;
    u16* Wqb = (u16*)d_out;                // d_out as scratch; out_proj rewrites it
    u16* Wkb = Wqb + 1048576ULL;
    u16* Wvb = Wqb + 2097152ULL;
    u16* Wob = Qw;                         // Qw dead after attn

    // X, W -> bf16
    cvt_bf16_kernel<<<1024, 256, 0, stream>>>(q, Xqb, 1048576);
    cvt_bf16_kernel<<<1024, 256, 0, stream>>>(k, Xkb, 1048576);
    cvt_bf16_kernel<<<1024, 256, 0, stream>>>(v, Xvb, 1048576);
    cvt_bf16_kernel<<<512, 256, 0, stream>>>(wq, Wqb, 131072);
    cvt_bf16_kernel<<<512, 256, 0, stream>>>(wk, Wkb, 131072);
    cvt_bf16_kernel<<<512, 256, 0, stream>>>(wv, Wvb, 131072);

    qkv_proj_kernel<<<1536, 256, 0, stream>>>(Xqb, Xkb, Xvb, Wqb, Wkb, Wvb,
                                              bq, bk, bv, Qw, Kw, Vw);
    rel_perm_kernel<<<4096, 256, 0, stream>>>(rel, relb);    // overwrites Xkb/Xvb (dead)
    attn_kernel<<<512, 512, 0, stream>>>(Qw, Kw, Vw, relb, Ow);   // overwrites Xqb (dead)
    cvt_bf16_kernel<<<512, 256, 0, stream>>>(wo, Wob, 131072);    // into dead Qw region
    out_proj_kernel<<<512, 256, 0, stream>>>(Ow, Wob, bo, (float*)d_out);
}

// Round 6
// 435.826 us; speedup vs baseline: 1.1117x; 1.0390x over previous
//
#include <hip/hip_runtime.h>

// FlashMultiHeadAttention  B=4 S=2048 HIDDEN=1024 H=16 Dh=64 (fp32 I/O)
// r11: GEMM 2-phase restructure + coalesced epilogue.
//  (a) qkv/out_proj K-loop: double-buffered LDS, ONE barrier per K-step in the
//      T3-minimum ordering {stage(next) -> ds_read(cur)+MFMA -> barrier}. The
//      implicit vmcnt(0) drain now happens AFTER compute, so staging latency
//      overlaps MFMA (r10: stage was drained by a barrier BEFORE compute —
//      ~650cyc/K-step wall vs ~160cyc of MFMA; MfmaUtil 20%).
//  (b) qkv epilogue: C-tile repacked via LDS (reusing the 32KB dbuf), streamed
//      as contiguous 128-256B runs. r10 WRITE_SIZE 93MB vs 48MB ideal (partial
//      32B / 4KB-strided stores).
// ws (u16 elems, 96 MB): Qw[0,8M) Kw[8M,16M) Vt[16M,24M) Ow[24M,32M) rel'[32M,48M)
//     aliases: Xq_bf16 = Ow region, Xk/Xv_bf16 = rel' region, Wq/Wk/Wv_bf16 =
//     d_out scratch, Wo_bf16 = Qw region (dead after attn).

#define SEQ 2048
#define NH 16
#define DH 64
#define HID 1024
#define QSCALE 0.18033688011112f   // 0.125 * log2(e)

typedef short bf16x8 __attribute__((ext_vector_type(8)));
typedef float f32x4  __attribute__((ext_vector_type(4)));
typedef unsigned short u16;
typedef unsigned short u16x4 __attribute__((ext_vector_type(4)));
typedef unsigned short u16x8 __attribute__((ext_vector_type(8)));

__device__ __forceinline__ float b2f(u16 u) {
    union { unsigned i; float f; } x; x.i = ((unsigned)u) << 16; return x.f;
}
__device__ __forceinline__ u16 f2b(float f) {
    union { float f; unsigned i; } x; x.f = f;
    unsigned r = x.i + 0x7fffu + ((x.i >> 16) & 1u);
    return (u16)(r >> 16);
}

typedef const __attribute__((address_space(1))) unsigned int guint;
typedef __attribute__((address_space(3))) unsigned int luint;
__device__ __forceinline__ void gload_lds16(const u16* g, u16* l) {
    __builtin_amdgcn_global_load_lds((guint*)g, (luint*)l, 16, 0, 0);
}

// ---------------- fp32 -> bf16 bulk convert (vectorized, grid-stride) ----------------
__global__ __launch_bounds__(256) void cvt_bf16_kernel(
    const float* __restrict__ in, u16* __restrict__ out, int n8)
{
    int i = blockIdx.x * 256 + threadIdx.x;
    const int stride = gridDim.x * 256;
    for (; i < n8; i += stride) {
        f32x4 a = *(const f32x4*)(in + (size_t)i * 8);
        f32x4 b = *(const f32x4*)(in + (size_t)i * 8 + 4);
        u16x8 o;
#pragma unroll
        for (int j = 0; j < 4; ++j) { o[j] = f2b(a[j]); o[j + 4] = f2b(b[j]); }
        *(u16x8*)(out + (size_t)i * 8) = o;
    }
}

// ---------------- rel -> bf16, pre-scaled, permuted to MFMA C-fragment order ----------
// out[b][qt16 (128)][kt64 (32)][lane (64)][nt (4)][g (4)]  where for element (q,k):
//   qt16=q>>4, kt64=k>>6, lane=((q>>2)&3)*16 + (k&15), nt=(k>>4)&3, g=q&3
__global__ __launch_bounds__(256) void rel_perm_kernel(
    const float* __restrict__ rel, u16* __restrict__ out)
{
    __shared__ u16 pl[4096];             // 4 qt16-subtiles x 1024
    const int t   = threadIdx.x;
    const int blk = blockIdx.x;          // 4096 = 4b x 32qc x 32kc
    const int b   = blk >> 10;
    const int qc  = (blk >> 5) & 31;
    const int kc  = blk & 31;
    const int qloc  = t >> 2;            // 0..63
    const int kloc0 = (t & 3) << 4;      // 0,16,32,48

    const float* src = rel + ((size_t)b * SEQ + qc * 64 + qloc) * SEQ + kc * 64 + kloc0;
    const int qt   = qloc >> 4;
    const int quad = (qloc >> 2) & 3;
    const int g    = qloc & 3;
    const int nt   = t & 3;
    u16* dst = pl + qt * 1024 + quad * 256 + nt * 4 + g;
#pragma unroll
    for (int c = 0; c < 4; ++c) {
        f32x4 x = *(const f32x4*)(src + c * 4);
#pragma unroll
        for (int j = 0; j < 4; ++j)
            dst[(c * 4 + j) * 16] = f2b(x[j] * QSCALE);
    }
    __syncthreads();
    const size_t obase = (((size_t)b * 128 + qc * 4) * 32 + kc) * 1024;
#pragma unroll
    for (int q2 = 0; q2 < 4; ++q2)
        *(u16x4*)(out + obase + (size_t)q2 * 32768 + t * 4) =
            *(const u16x4*)(pl + q2 * 1024 + t * 4);
}

// swizzled chunk offset within a 32-elem (64B) LDS row, for row R, chunk c (0..3):
//   elem_off = ((c ^ ((R>>1)&3)) << 3)
#define GSWZ(R, C) (((R) << 5) + ((((C) ^ (((R) >> 1) & 3))) << 3))

// ---------------- QKV projection: bf16 2-phase dbuf GEMM, Y = X @ W^T + b ----------------
__global__ __launch_bounds__(256) void qkv_proj_kernel(
    const u16* __restrict__ xq, const u16* __restrict__ xk, const u16* __restrict__ xv,
    const u16* __restrict__ wq, const u16* __restrict__ wk, const u16* __restrict__ wv,
    const float* __restrict__ bq, const float* __restrict__ bk, const float* __restrict__ bv,
    u16* __restrict__ Qw, u16* __restrict__ Kw, u16* __restrict__ Vw)
{
    __shared__ __align__(16) u16 sm[16384];   // As0|As1|Bs0|Bs1 (4KB-rows x4); repack reuse

    const int tid  = threadIdx.x;
    const int w    = tid >> 6;
    const int lane = tid & 63;
    const int l16  = lane & 15;
    const int quad = lane >> 4;

    // XCD-aware bijective remap: 1536 blocks, 8 XCDs, 192 contiguous each
    const int lbid = ((blockIdx.x & 7) * 192) + (blockIdx.x >> 3);
    const int sel = lbid >> 9;           // 0=q 1=k 2=v  (512 blocks each)
    const int rem = lbid & 511;
    const int tm = rem >> 3, tn = rem & 7;
    const int m0 = tm << 7, n0 = tn << 7;

    const u16* X    = sel == 0 ? xq : (sel == 1 ? xk : xv);
    const u16* W    = sel == 0 ? wq : (sel == 1 ? wk : wv);
    const float* bias = sel == 0 ? bq : (sel == 1 ? bk : bv);

    const int crow = lane >> 2;                          // row within chunk 0..15
    // pre-swizzled GLOBAL chunk: lane l writes LDS chunk l&3, must fetch
    // global chunk (l&3) ^ ((l>>3)&3)  (matches GSWZ read-back)
    const int csw  = (((lane & 3) ^ ((lane >> 3) & 3)) << 3);

    f32x4 acc[4][4];
    const f32x4 zero = {0.f, 0.f, 0.f, 0.f};
#pragma unroll
    for (int r = 0; r < 4; ++r)
#pragma unroll
        for (int c = 0; c < 4; ++c) acc[r][c] = zero;

    const int wr = (w >> 1) << 6;
    const int wc = (w & 1) << 6;

    // ---- 2-phase double-buffered K-loop: one barrier per K-step ----
    {
        // prologue: stage buf0 (k0=0)
#pragma unroll
        for (int c = 0; c < 2; ++c) {
            const int ch  = w + c * 4;
            const int row = ch * 16 + crow;
            gload_lds16(X + (size_t)(m0 + row) * 1024 + csw, sm + ch * 512 + lane * 8);
            gload_lds16(W + (size_t)(n0 + row) * 1024 + csw, sm + 8192 + ch * 512 + lane * 8);
        }
        __syncthreads();
    }
    for (int t = 0; t < 32; ++t) {
        if (t < 31) {
            const int kn = (t + 1) << 5;
            u16* a = sm + (((t + 1) & 1) << 12);
            u16* bL = sm + 8192 + (((t + 1) & 1) << 12);
#pragma unroll
            for (int c = 0; c < 2; ++c) {
                const int ch  = w + c * 4;
                const int row = ch * 16 + crow;
                gload_lds16(X + (size_t)(m0 + row) * 1024 + kn + csw, a + ch * 512 + lane * 8);
                gload_lds16(W + (size_t)(n0 + row) * 1024 + kn + csw, bL + ch * 512 + lane * 8);
            }
        }
        const u16* As_ = sm + ((t & 1) << 12);
        const u16* Bs_ = sm + 8192 + ((t & 1) << 12);
        bf16x8 a[4], b[4];
#pragma unroll
        for (int r = 0; r < 4; ++r) {
            const int R = wr + r * 16 + l16;
            a[r] = *(const bf16x8*)(As_ + GSWZ(R, quad));
        }
#pragma unroll
        for (int c = 0; c < 4; ++c) {
            const int R = wc + c * 16 + l16;
            b[c] = *(const bf16x8*)(Bs_ + GSWZ(R, quad));
        }
#pragma unroll
        for (int r = 0; r < 4; ++r)
#pragma unroll
            for (int c = 0; c < 4; ++c)
                acc[r][c] = __builtin_amdgcn_mfma_f32_16x16x32_bf16(a[r], b[c], acc[r][c], 0, 0, 0);
        __syncthreads();   // implicit vmcnt(0)+lgkmcnt(0) drain AFTER compute
    }

    // ---- epilogue: repack C-tile via LDS (reuse sm), stream contiguous runs ----
    // C layout: col(n)=lane&15, row(m)=quad*4+reg
    const int b_ = m0 >> 11;
    const int s0 = m0 & 2047;
    const int h0 = n0 >> 6;
    const float qsc = (sel == 0) ? QSCALE : 1.0f;

    if (sel < 2) {
        // LDS[mloc][nloc], stride 128
#pragma unroll
        for (int c = 0; c < 4; ++c) {
            const int nloc = wc + c * 16 + l16;
            const float bn = bias[n0 + nloc];
#pragma unroll
            for (int r = 0; r < 4; ++r)
#pragma unroll
                for (int g = 0; g < 4; ++g) {
                    const int mloc = wr + r * 16 + quad * 4 + g;
                    sm[mloc * 128 + nloc] = f2b((acc[r][c][g] + bn) * qsc);
                }
        }
        __syncthreads();
        u16* dst = (sel == 0) ? Qw : Kw;
#pragma unroll
        for (int i = 0; i < 8; ++i) {
            const int ci = i * 256 + tid;
            const int mloc = ci >> 4, cl = ci & 15;
            u16x8 vch = *(const u16x8*)(sm + mloc * 128 + cl * 8);
            *(u16x8*)(dst + (((size_t)(b_ * 16 + h0 + (cl >> 3))) * 2048 + s0 + mloc) * 64
                          + (cl & 7) * 8) = vch;
        }
    } else {
        // V transposed: LDS[nloc][mloc], stride 128
#pragma unroll
        for (int c = 0; c < 4; ++c) {
            const int nloc = wc + c * 16 + l16;
            const float bn = bias[n0 + nloc];
#pragma unroll
            for (int r = 0; r < 4; ++r)
#pragma unroll
                for (int g = 0; g < 4; ++g) {
                    const int mloc = wr + r * 16 + quad * 4 + g;
                    sm[nloc * 128 + mloc] = f2b(acc[r][c][g] + bn);
                }
        }
        __syncthreads();
#pragma unroll
        for (int i = 0; i < 8; ++i) {
            const int ci = i * 256 + tid;
            const int nloc = ci >> 4, cl = ci & 15;
            u16x8 vch = *(const u16x8*)(sm + nloc * 128 + cl * 8);
            *(u16x8*)(Vw + (((size_t)(b_ * 16 + h0 + (nloc >> 6))) * 64 + (nloc & 63)) * 2048
                          + s0 + cl * 8) = vch;
        }
    }
}

// swizzled LDS addr for 64-wide u16 rows: 16B chunk index XORed with row&7
#define SWZ(R, C) (((R) << 6) + ((((C) ^ ((R) & 7))) << 3))

// ---------------- Flash attention: 8 waves/block, 16 q/wave, 2 strips/block ----------------
// double-buffered K/V LDS, 1 barrier per tile, swizzled conflict-free layout
__global__ __launch_bounds__(512, 4) void attn_kernel(
    const u16* __restrict__ Qb, const u16* __restrict__ Kb,
    const u16* __restrict__ Vb, const u16* __restrict__ relb,
    u16* __restrict__ Ob)
{
    __shared__ __align__(16) u16 lds[25600];   // Ks[2]:4096 ea | Vt[2]:4096 ea | Pl 8x1152
    const int tid  = threadIdx.x;              // 0..511
    const int w    = tid >> 6;                 // 0..7
    const int lane = tid & 63;
    const int l16  = lane & 15;
    const int quad = lane >> 4;
    u16* Pl = lds + 16384 + w * 1152;          // 16 rows x 72

    const int bh = blockIdx.x & 63;
    const int p  = blockIdx.x >> 6;            // 0..7 strip pair
    const int b  = bh >> 4, h = bh & 15;

    const u16* Qp = Qb + (size_t)bh * SEQ * DH;
    const u16* Kg = Kb + (size_t)bh * SEQ * DH;
    const u16* Vg = Vb + (size_t)bh * DH * SEQ;

    // staging: 512 16B-chunks per tile kind, exactly 1 per thread
    const int r0 = tid >> 3;                   // row 0..63
    const int c0 = tid & 7;                    // chunk 0..7
    const int o0 = c0 << 3;                    // linear elem offset (global src)
    const int sw0 = ((c0 ^ (r0 & 7)) << 3);    // swizzled elem offset (LDS dst)

    for (int sidx = 0; sidx < 2; ++sidx) {
        const int qb  = sidx ? (15 - p) : p;
        const int q0w = qb * 128 + w * 16;     // wave's 16-query window

        // Q A-fragments (persistent; Q pre-scaled by QSCALE)
        bf16x8 qa[2];
#pragma unroll
        for (int ks = 0; ks < 2; ++ks)
            qa[ks] = *(const bf16x8*)(Qp + (size_t)(q0w + l16) * 64 + ks * 32 + quad * 8);

        f32x4 o[4], mrow, lrow;
        const f32x4 zero = {0.f, 0.f, 0.f, 0.f};
        const f32x4 ninf = {-1e30f, -1e30f, -1e30f, -1e30f};
        mrow = ninf; lrow = zero;
#pragma unroll
        for (int dt = 0; dt < 4; ++dt) o[dt] = zero;

        const int ntiles  = qb * 2 + 2;              // staged by the block (always even)
        const int mytiles = qb * 2 + (w >> 2) + 1;   // processed by this wave

        // rel (permuted) base: idx = (b*128+qt)*32768 + kt*1024 + lane*16
        const u16* relW = relb + ((size_t)(b * 128 + (q0w >> 4))) * 32768 + (size_t)lane * 16;

        // prefetch tile 0
        bf16x8 kreg = *(const bf16x8*)(Kg + (size_t)r0 * 64 + o0);
        bf16x8 vreg = *(const bf16x8*)(Vg + (size_t)r0 * 2048 + o0);
        bf16x8 rr0 = *(const bf16x8*)(relW);
        bf16x8 rr1 = *(const bf16x8*)(relW + 8);

        for (int kt = 0; kt < ntiles; ++kt) {
            const int k0 = kt << 6;
            u16* Ksb = lds + ((kt & 1) << 12);
            u16* Vtb = lds + 8192 + ((kt & 1) << 12);
            // regs -> LDS buf[kt&1] (swizzled)
            *(bf16x8*)(Ksb + r0 * 64 + sw0) = kreg;
            *(bf16x8*)(Vtb + r0 * 64 + sw0) = vreg;

            const bool act = kt < mytiles;
            // s-init from prefetched rel regs (pure VALU, before barrier)
            f32x4 s[4];
            if (act) {
#pragma unroll
                for (int nt = 0; nt < 4; ++nt)
#pragma unroll
                    for (int g = 0; g < 4; ++g)
                        s[nt][g] = b2f((u16)((nt < 2 ? rr0 : rr1)[(nt & 1) * 4 + g]));
            }

            // issue next tile's global loads (latency hidden under compute)
            const int ktn = (kt + 1 < ntiles) ? kt + 1 : kt;
            const int kn  = ktn << 6;
            kreg = *(const bf16x8*)(Kg + (size_t)(kn + r0) * 64 + o0);
            vreg = *(const bf16x8*)(Vg + (size_t)r0 * 2048 + kn + o0);
            rr0  = *(const bf16x8*)(relW + (size_t)ktn * 1024);
            rr1  = *(const bf16x8*)(relW + (size_t)ktn * 1024 + 8);

            __syncthreads();   // single barrier: buf[kt&1] ready; WAR separated by next barrier

            if (act) {
                // ---- scores: C init = rel' (done above), MFMA adds scaled QK^T ----
#pragma unroll
                for (int nt = 0; nt < 4; ++nt) {
                    const int R = nt * 16 + l16;
                    bf16x8 kb0 = *(const bf16x8*)(Ksb + SWZ(R, quad));
                    bf16x8 kb1 = *(const bf16x8*)(Ksb + SWZ(R, 4 | quad));
                    s[nt] = __builtin_amdgcn_mfma_f32_16x16x32_bf16(qa[0], kb0, s[nt], 0, 0, 0);
                    s[nt] = __builtin_amdgcn_mfma_f32_16x16x32_bf16(qa[1], kb1, s[nt], 0, 0, 0);
                }
                // ---- causal mask (diagonal tile only) ----
                if (kt == mytiles - 1) {
#pragma unroll
                    for (int nt = 0; nt < 4; ++nt)
#pragma unroll
                        for (int g = 0; g < 4; ++g) {
                            const int q = q0w + quad * 4 + g;
                            const int k = k0 + nt * 16 + l16;
                            if (k > q) s[nt][g] = -1e30f;
                        }
                }
                // ---- online softmax (exp2 domain); row-sum deferred to epilogue ----
                {
                    f32x4 t;
#pragma unroll
                    for (int g = 0; g < 4; ++g)
                        t[g] = fmaxf(fmaxf(s[0][g], s[1][g]), fmaxf(s[2][g], s[3][g]));
#pragma unroll
                    for (int off = 1; off < 16; off <<= 1)
#pragma unroll
                        for (int g = 0; g < 4; ++g)
                            t[g] = fmaxf(t[g], __shfl_xor(t[g], off, 64));
                    f32x4 mn, alpha;
#pragma unroll
                    for (int g = 0; g < 4; ++g) {
                        mn[g] = fmaxf(mrow[g], t[g]);
                        alpha[g] = __builtin_amdgcn_exp2f(mrow[g] - mn[g]);
                    }
                    mrow = mn;
#pragma unroll
                    for (int dt = 0; dt < 4; ++dt)
#pragma unroll
                        for (int g = 0; g < 4; ++g) o[dt][g] *= alpha[g];
#pragma unroll
                    for (int nt = 0; nt < 4; ++nt)
#pragma unroll
                        for (int g = 0; g < 4; ++g)
                            s[nt][g] = __builtin_amdgcn_exp2f(s[nt][g] - mn[g]);
                    // lane-local partial row-sum (alpha is row-uniform -> consistent)
#pragma unroll
                    for (int g = 0; g < 4; ++g)
                        lrow[g] = lrow[g] * alpha[g]
                                + ((s[0][g] + s[1][g]) + (s[2][g] + s[3][g]));
                }
                // ---- P -> bf16 -> per-wave LDS ----
#pragma unroll
                for (int nt = 0; nt < 4; ++nt)
#pragma unroll
                    for (int g = 0; g < 4; ++g)
                        Pl[(quad * 4 + g) * 72 + nt * 16 + l16] = f2b(s[nt][g]);
                // ---- PV ----
                bf16x8 pa[2];
#pragma unroll
                for (int ks = 0; ks < 2; ++ks)
                    pa[ks] = *(const bf16x8*)(Pl + l16 * 72 + ks * 32 + quad * 8);
#pragma unroll
                for (int dt = 0; dt < 4; ++dt) {
                    const int R = dt * 16 + l16;
                    bf16x8 vb0 = *(const bf16x8*)(Vtb + SWZ(R, quad));
                    bf16x8 vb1 = *(const bf16x8*)(Vtb + SWZ(R, 4 | quad));
                    o[dt] = __builtin_amdgcn_mfma_f32_16x16x32_bf16(pa[0], vb0, o[dt], 0, 0, 0);
                    o[dt] = __builtin_amdgcn_mfma_f32_16x16x32_bf16(pa[1], vb1, o[dt], 0, 0, 0);
                }
            }
        }

        // ---- epilogue: reduce lrow across the 16-lane k-groups, then store ----
#pragma unroll
        for (int off = 1; off < 16; off <<= 1)
#pragma unroll
            for (int g = 0; g < 4; ++g)
                lrow[g] += __shfl_xor(lrow[g], off, 64);
        {
            f32x4 linv;
#pragma unroll
            for (int g = 0; g < 4; ++g) linv[g] = 1.0f / lrow[g];
#pragma unroll
            for (int dt = 0; dt < 4; ++dt)
#pragma unroll
                for (int g = 0; g < 4; ++g)
                    Pl[(quad * 4 + g) * 72 + dt * 16 + l16] = f2b(o[dt][g] * linv[g]);
        }
#pragma unroll
        for (int pp = 0; pp < 2; ++pp) {
            const int c = lane + pp * 64;
            const int row = c >> 3, col = (c & 7) << 3;
            bf16x8 t = *(const bf16x8*)(Pl + row * 72 + col);
            *(bf16x8*)(Ob + ((size_t)b * SEQ + q0w + row) * HID + h * DH + col) = t;
        }
    }
}

// ---------------- Output projection: bf16 2-phase dbuf GEMM, out = O @ Wout^T + bout ----
__global__ __launch_bounds__(256) void out_proj_kernel(
    const u16* __restrict__ X, const u16* __restrict__ W,
    const float* __restrict__ bias, float* __restrict__ out)
{
    __shared__ __align__(16) u16 sm[16384];

    const int tid  = threadIdx.x;
    const int w    = tid >> 6;
    const int lane = tid & 63;
    const int l16  = lane & 15;
    const int quad = lane >> 4;

    // XCD-aware bijective remap: 512 blocks, 64 contiguous per XCD
    const int lbid = ((blockIdx.x & 7) * 64) + (blockIdx.x >> 3);
    const int tm = lbid >> 3, tn = lbid & 7;
    const int m0 = tm << 7, n0 = tn << 7;

    const int crow = lane >> 2;
    const int csw  = (((lane & 3) ^ ((lane >> 3) & 3)) << 3);

    f32x4 acc[4][4];
    const f32x4 zero = {0.f, 0.f, 0.f, 0.f};
#pragma unroll
    for (int r = 0; r < 4; ++r)
#pragma unroll
        for (int c = 0; c < 4; ++c) acc[r][c] = zero;

    const int wr = (w >> 1) << 6;
    const int wc = (w & 1) << 6;

    {
#pragma unroll
        for (int c = 0; c < 2; ++c) {
            const int ch  = w + c * 4;
            const int row = ch * 16 + crow;
            gload_lds16(X + (size_t)(m0 + row) * 1024 + csw, sm + ch * 512 + lane * 8);
            gload_lds16(W + (size_t)(n0 + row) * 1024 + csw, sm + 8192 + ch * 512 + lane * 8);
        }
        __syncthreads();
    }
    for (int t = 0; t < 32; ++t) {
        if (t < 31) {
            const int kn = (t + 1) << 5;
            u16* a = sm + (((t + 1) & 1) << 12);
            u16* bL = sm + 8192 + (((t + 1) & 1) << 12);
#pragma unroll
            for (int c = 0; c < 2; ++c) {
                const int ch  = w + c * 4;
                const int row = ch * 16 + crow;
                gload_lds16(X + (size_t)(m0 + row) * 1024 + kn + csw, a + ch * 512 + lane * 8);
                gload_lds16(W + (size_t)(n0 + row) * 1024 + kn + csw, bL + ch * 512 + lane * 8);
            }
        }
        const u16* As_ = sm + ((t & 1) << 12);
        const u16* Bs_ = sm + 8192 + ((t & 1) << 12);
        bf16x8 a[4], b[4];
#pragma unroll
        for (int r = 0; r < 4; ++r) {
            const int R = wr + r * 16 + l16;
            a[r] = *(const bf16x8*)(As_ + GSWZ(R, quad));
        }
#pragma unroll
        for (int c = 0; c < 4; ++c) {
            const int R = wc + c * 16 + l16;
            b[c] = *(const bf16x8*)(Bs_ + GSWZ(R, quad));
        }
#pragma unroll
        for (int r = 0; r < 4; ++r)
#pragma unroll
            for (int c = 0; c < 4; ++c)
                acc[r][c] = __builtin_amdgcn_mfma_f32_16x16x32_bf16(a[r], b[c], acc[r][c], 0, 0, 0);
        __syncthreads();
    }

#pragma unroll
    for (int c = 0; c < 4; ++c) {
        const int n = n0 + wc + c * 16 + l16;
        const float bn = bias[n];
#pragma unroll
        for (int r = 0; r < 4; ++r) {
#pragma unroll
            for (int g = 0; g < 4; ++g) {
                const int m = m0 + wr + r * 16 + quad * 4 + g;
                out[(size_t)m * 1024 + n] = acc[r][c][g] + bn;
            }
        }
    }
}

extern "C" void kernel_launch(void* const* d_in, const int* in_sizes, int n_in,
                              void* d_out, int out_size, void* d_ws, size_t ws_size,
                              hipStream_t stream)
{
    const float* q   = (const float*)d_in[0];
    const float* k   = (const float*)d_in[1];
    const float* v   = (const float*)d_in[2];
    const float* rel = (const float*)d_in[3];
    // d_in[4] = attn_mask: statically causal tril, not read
    const float* wq = (const float*)d_in[5];  const float* bq = (const float*)d_in[6];
    const float* wk = (const float*)d_in[7];  const float* bk = (const float*)d_in[8];
    const float* wv = (const float*)d_in[9];  const float* bv = (const float*)d_in[10];
    const float* wo = (const float*)d_in[11]; const float* bo = (const float*)d_in[12];

    u16* ws = (u16*)d_ws;                 // 96 MB used
    u16* Qw   = ws;
    u16* Kw   = ws + 8388608ULL;
    u16* Vw   = ws + 16777216ULL;
    u16* Ow   = ws + 25165824ULL;
    u16* relb = ws + 33554432ULL;

    // bf16 staging aliases (dead by the time their hosts are written):
    u16* Xqb = Ow;                         // overwritten by attn (after qkv)
    u16* Xkb = relb;                       // overwritten by rel_perm (after qkv)
    u16* Xvb = relb + 8388608ULL;
    u16* Wqb = (u16*)d_out;                // d_out as scratch; out_proj rewrites it
    u16* Wkb = Wqb + 1048576ULL;
    u16* Wvb = Wqb + 2097152ULL;
    u16* Wob = Qw;                         // Qw dead after attn

    // X, W -> bf16
    cvt_bf16_kernel<<<1024, 256, 0, stream>>>(q, Xqb, 1048576);
    cvt_bf16_kernel<<<1024, 256, 0, stream>>>(k, Xkb, 1048576);
    cvt_bf16_kernel<<<1024, 256, 0, stream>>>(v, Xvb, 1048576);
    cvt_bf16_kernel<<<512, 256, 0, stream>>>(wq, Wqb, 131072);
    cvt_bf16_kernel<<<512, 256, 0, stream>>>(wk, Wkb, 131072);
    cvt_bf16_kernel<<<512, 256, 0, stream>>>(wv, Wvb, 131072);

    qkv_proj_kernel<<<1536, 256, 0, stream>>>(Xqb, Xkb, Xvb, Wqb, Wkb, Wvb,
                                              bq, bk, bv, Qw, Kw, Vw);
    rel_perm_kernel<<<4096, 256, 0, stream>>>(rel, relb);    // overwrites Xkb/Xvb (dead)
    attn_kernel<<<512, 512, 0, stream>>>(Qw, Kw, Vw, relb, Ow);   // overwrites Xqb (dead)
    cvt_bf16_kernel<<<512, 256, 0, stream>>>(wo, Wob, 131072);    // into dead Qw region
    out_proj_kernel<<<512, 256, 0, stream>>>(Ow, Wob, bo, (float*)d_out);
}